// Round 14
// baseline (45245.642 us; speedup 1.0000x reference)
//
#include <hip/hip_runtime.h>

namespace {
constexpr int kB  = 32;
constexpr int kT  = 1024;
constexpr int kD  = 512;
constexpr int kH  = 1024;
constexpr int kLV = 128;
constexpr int kNG = 4 * kH + 2 * kLV;   // 4352
constexpr int kNBLK = 256;
constexpr int kNTHR = 512;
// ws float offsets (r9)
constexpr int kOffH0 = 8192;
constexpr int kOffWF = kOffH0 + 2 * kB * kH + 2 * kB * kNG;
// LDS byte offsets
constexpr int kRedOff = 3 * 1536 * 2 * 16;   // weight region max: 147456 B
constexpr int kIhOff  = kRedOff + 6144;      // red: 2rt x 3u x 64 lanes x 16B
constexpr int kFhOff  = kIhOff + 512;
constexpr int kSmxOff = kFhOff + 512;
constexpr int kLdsBytes = kSmxOff + 32;      // 154,656 <= 163,840
}

typedef float vfloat4 __attribute__((ext_vector_type(4)));
typedef float floatx4 __attribute__((ext_vector_type(4)));
typedef _Float16 half8_t __attribute__((ext_vector_type(8)));
typedef unsigned short ushort_t;

static __device__ __forceinline__ unsigned ld_flag(const unsigned* p) {
  return __hip_atomic_load(p, __ATOMIC_RELAXED, __HIP_MEMORY_SCOPE_AGENT);
}
static __device__ __forceinline__ void st_flag(unsigned* p, unsigned v) {
  __hip_atomic_store(p, v, __ATOMIC_RELAXED, __HIP_MEMORY_SCOPE_AGENT);
}
static __device__ __forceinline__ void st_wt(float* p, float v) {
  asm volatile("global_store_dword %0, %1, off sc0 sc1" :: "v"(p), "v"(v) : "memory");
}
// 16 PLAIN cached 16B loads (L2-shared per XCD; coherence via acquire fence
// at barrier exit): 8 MFMA A-frag m-steps at stride 512B from one base.
// All completed INSIDE one asm block (proven pattern r5-r13).
static __device__ __forceinline__ void ld16h(vfloat4 v[16], const float* b) {
  asm volatile(
      "global_load_dwordx4 %0,  %16, off\n\t"
      "global_load_dwordx4 %1,  %16, off offset:16\n\t"
      "global_load_dwordx4 %2,  %16, off offset:512\n\t"
      "global_load_dwordx4 %3,  %16, off offset:528\n\t"
      "global_load_dwordx4 %4,  %16, off offset:1024\n\t"
      "global_load_dwordx4 %5,  %16, off offset:1040\n\t"
      "global_load_dwordx4 %6,  %16, off offset:1536\n\t"
      "global_load_dwordx4 %7,  %16, off offset:1552\n\t"
      "global_load_dwordx4 %8,  %16, off offset:2048\n\t"
      "global_load_dwordx4 %9,  %16, off offset:2064\n\t"
      "global_load_dwordx4 %10, %16, off offset:2560\n\t"
      "global_load_dwordx4 %11, %16, off offset:2576\n\t"
      "global_load_dwordx4 %12, %16, off offset:3072\n\t"
      "global_load_dwordx4 %13, %16, off offset:3088\n\t"
      "global_load_dwordx4 %14, %16, off offset:3584\n\t"
      "global_load_dwordx4 %15, %16, off offset:3600\n\t"
      "s_waitcnt vmcnt(0)"
      : "=&v"(v[0]), "=&v"(v[1]), "=&v"(v[2]), "=&v"(v[3]),
        "=&v"(v[4]), "=&v"(v[5]), "=&v"(v[6]), "=&v"(v[7]),
        "=&v"(v[8]), "=&v"(v[9]), "=&v"(v[10]), "=&v"(v[11]),
        "=&v"(v[12]), "=&v"(v[13]), "=&v"(v[14]), "=&v"(v[15])
      : "v"(b)
      : "memory");
}
static __device__ __forceinline__ unsigned pkrtz(float a, float b) {
  return __builtin_bit_cast(unsigned, __builtin_amdgcn_cvt_pkrtz(a, b));
}
static __device__ __forceinline__ uint4 pack2(vfloat4 a, vfloat4 b) {
  uint4 r;
  r.x = pkrtz(a.x, a.y); r.y = pkrtz(a.z, a.w);
  r.z = pkrtz(b.x, b.y); r.w = pkrtz(b.z, b.w);
  return r;
}
static __device__ __forceinline__ floatx4 mfma16(uint4 a, uint4 b, floatx4 c) {
  return __builtin_amdgcn_mfma_f32_16x16x32_f16(
      __builtin_bit_cast(half8_t, a), __builtin_bit_cast(half8_t, b), c, 0, 0, 0);
}

// -------- fp32 -> fp16 weight conversion (one-time pre-pass) --------
__global__ __launch_bounds__(256) void cvt_fp16_kernel(
    const float* __restrict__ src, ushort_t* __restrict__ dst, int n8) {
  int i = blockIdx.x * 256 + threadIdx.x;
  if (i >= n8) return;
  const vfloat4* s4 = (const vfloat4*)src;
  vfloat4 a = s4[2 * i], b = s4[2 * i + 1];
  typedef _Float16 h8 __attribute__((ext_vector_type(8)));
  h8 o;
  o[0] = (_Float16)a.x; o[1] = (_Float16)a.y;
  o[2] = (_Float16)a.z; o[3] = (_Float16)a.w;
  o[4] = (_Float16)b.x; o[5] = (_Float16)b.y;
  o[6] = (_Float16)b.z; o[7] = (_Float16)b.w;
  ((h8*)dst)[i] = o;
}

__global__ __launch_bounds__(kNTHR, 2) void onlstm_kernel(
    const float* __restrict__ x,
    const float* __restrict__ bl0, const float* __restrict__ bv0,
    const float* __restrict__ bl1, const float* __restrict__ bv1,
    const ushort_t* __restrict__ wf0u, const ushort_t* __restrict__ wf1u,
    float* __restrict__ out, float* __restrict__ ws)
{
  const int tid = threadIdx.x;
  const int bid = blockIdx.x;

  // ---- workspace (r9) ----
  unsigned* flags = (unsigned*)ws;
  unsigned* genp  = (unsigned*)ws + 4096;
  float* h0     = ws + kOffH0;
  float* h1     = h0 + kB * kH;
  float* gates0 = h1 + kB * kH;
  float* gates1 = gates0 + kB * kNG;

  __shared__ __align__(16) char sb[kLdsBytes];
  uint4* wb4   = (uint4*)sb;                    // weight B-fragments
  float* redp  = (float*)(sb + kRedOff);        // K-stripe reduce
  float* ih_sh = (float*)(sb + kIhOff);
  float* fh_sh = (float*)(sb + kFhOff);
  float* smx   = (float*)(sb + kSmxOff);

  unsigned seq = 0;
  // flags-only barrier (r8-r13) + ACQUIRE fence on exit: producers write-
  // through (st_wt) + drain vmcnt before flag; consumers invalidate stale
  // L1/L2 here, then use PLAIN cached loads (L2-shared within each XCD).
  auto gridbar = [&]() {
    ++seq;
    asm volatile("s_waitcnt vmcnt(0)" ::: "memory");
    __syncthreads();
    if (bid == 0) {
      if (tid >= 1 && tid < kNBLK) {
        while (ld_flag(&flags[tid * 16]) != seq) __builtin_amdgcn_s_sleep(2);
      }
      __syncthreads();
      if (tid == 0) st_flag(genp, seq);
    } else {
      if (tid == 0) {
        st_flag(&flags[bid * 16], seq);
        while (ld_flag(genp) != seq) __builtin_amdgcn_s_sleep(2);
      }
      __syncthreads();
    }
    __builtin_amdgcn_fence(__ATOMIC_ACQUIRE, "agent");
    asm volatile("" ::: "memory");
  };

  // ---- A-phase block type ----
  int L, ntile, cb0;
  if (bid < 32)       { L = 0; ntile = 3; cb0 = bid * 48; }
  else if (bid < 120) { L = 0; ntile = 2; cb0 = 1536 + (bid - 32) * 32; }
  else                { L = 1; ntile = 2; cb0 = (bid - 120) * 32; }
  const int K   = L ? 2048 : 1536;
  const int ts4 = K * 2;                        // uint4 per weight tile
  const bool three = (ntile == 3);
  const ushort_t* wf = L ? wf1u : wf0u;
  const float* blp = L ? bl1 : bl0;
  const float* bvp = L ? bv1 : bv0;
  float* gatesL = L ? gates1 : gates0;

  // wave mapping: rt = row-half, str = K-quarter
  const int lane = tid & 63;
  const int rt   = (tid >> 6) & 1;
  const int str  = tid >> 7;
  const int r_   = rt * 16 + (lane & 15);       // batch row (A-frag row)
  const int koct = lane >> 4;                   // k-octet within 32-k window
  const int colg0 = cb0 + (lane & 15);
  const int colg1 = cb0 + 16 + (lane & 15);
  const int colg2 = cb0 + 32 + (lane & 15);

  // ---- one-time: build weight B-fragments in LDS (lane-linear; r12-proven) ----
  for (int tt = 0; tt < ntile; ++tt) {
    const int colb = cb0 + tt * 16;
    for (int idx = tid; idx < ts4; idx += kNTHR) {
      int m = idx >> 6, l2 = idx & 63;
      size_t off = (size_t)(colb + (l2 & 15)) * K + m * 32 + 8 * (l2 >> 4);
      wb4[tt * ts4 + idx] = *(const uint4*)(wf + off);
    }
  }
  const float b0w = (colg0 < 4096) ? blp[colg0] : bvp[colg0 - 4096];
  const float b1w = (colg1 < 4096) ? blp[colg1] : bvp[colg1 - 4096];
  const float b2w = three ? ((colg2 < 4096) ? blp[colg2] : bvp[colg2 - 4096]) : 0.f;
  __syncthreads();

  // zero h0,h1
  { int idx = bid * kNTHR + tid; if (idx < 2 * kB * kH) st_wt(h0 + idx, 0.f); }
  float creg = 0.f;
  gridbar();

  // phase-B cell update (r9-proven structure; plain cached gate loads)
  const int pbB  = (bid & 127) >> 2;
  const int qq4B = bid & 3;
  auto cellB = [&](const float* gbase, float* hb, float& cr, float* outp, int t) {
    const float* gr = gbase + (size_t)pbB * kNG;
    const int wl = tid & 63, wv2 = tid >> 6;
    const bool sm = tid < 128;
    const bool cl = tid < 256;
    float vi = 0.f, vf = 0.f, vo = 0.f, vg = 0.f;
    int j = qq4B * 256 + tid;
    if (cl) {
      vi = gr[j];
      vf = gr[kH + j];
      vo = gr[2 * kH + j];
      vg = gr[3 * kH + j];
    }
    float ai = 0.f, af = 0.f;
    if (sm) { ai = gr[4096 + tid]; af = gr[4096 + kLV + tid]; }
    float mi = ai, mf = af;
    if (sm) {
#pragma unroll
      for (int d2 = 32; d2 > 0; d2 >>= 1) {
        mi = fmaxf(mi, __shfl_xor(mi, d2));
        mf = fmaxf(mf, __shfl_xor(mf, d2));
      }
      if (wl == 0) { smx[wv2] = mi; smx[2 + wv2] = mf; }
    }
    __syncthreads();
    mi = fmaxf(smx[0], smx[1]);
    mf = fmaxf(smx[2], smx[3]);
    float ei = 0.f, Pi = 0.f, Pf = 0.f;
    if (sm) {
      ei = __expf(ai - mi);
      float ef = __expf(af - mf);
      Pi = ei; Pf = ef;
#pragma unroll
      for (int d2 = 1; d2 < 64; d2 <<= 1) {
        float ni = __shfl_up(Pi, d2);
        float nf = __shfl_up(Pf, d2);
        if (wl >= d2) { Pi += ni; Pf += nf; }
      }
      if (wl == 63) { smx[4 + wv2] = Pi; smx[6 + wv2] = Pf; }
    }
    __syncthreads();
    float Si = smx[4] + smx[5], Sf = smx[6] + smx[7];
    if (sm) {
      if (wv2 == 1) { Pi += smx[4]; Pf += smx[6]; }
      ih_sh[tid] = Pf / Sf;
      fh_sh[tid] = (Si - Pi + ei) / Si;
    }
    __syncthreads();
    if (cl) {
      float i_ = 1.f / (1.f + __expf(-vi));
      float f_ = 1.f / (1.f + __expf(-vf));
      float o_ = 1.f / (1.f + __expf(-vo));
      float g_ = tanhf(vg);
      int l2 = j >> 3;
      float ih = ih_sh[l2], fh = fh_sh[l2];
      float w  = ih * fh;
      float cold = cr;
      float cn = w * (f_ * cold + i_ * g_) + (fh - w) * cold + (ih - w) * g_;
      float hn = o_ * tanhf(cn);
      cr = cn;
      st_wt(hb + (size_t)pbB * kH + j, hn);
      if (outp) st_wt(outp + ((size_t)pbB * kT + t) * kH + j, hn);
    }
  };

  for (int e = 0; e <= kT; ++e) {
    const bool actA = L ? (e >= 1) : (e < kT);

    // ========== Phase A: MFMA, zero syncs in K loop ==========
    if (actA) {
      floatx4 a0 = {0.f,0.f,0.f,0.f}, a1 = a0, a2 = a0;
      uint4 pa[8];
      if (L == 0) {
        // x segment: m-steps str+4j, j=0..3 (plain cached loads; x immutable)
        {
          const float* bx = x + ((size_t)r_ * kT + e) * kD + str * 32 + koct * 8;
          vfloat4 vx[8];
#pragma unroll
          for (int j = 0; j < 4; ++j) {
            vx[2*j]   = *(const vfloat4*)(bx + j * 128);
            vx[2*j+1] = *(const vfloat4*)(bx + j * 128 + 4);
          }
#pragma unroll
          for (int j = 0; j < 4; ++j) pa[j] = pack2(vx[2*j], vx[2*j+1]);
#pragma unroll
          for (int j = 0; j < 4; ++j) {
            const int m = str + 4 * j;
            a0 = mfma16(pa[j], wb4[m * 64 + lane], a0);
            a1 = mfma16(pa[j], wb4[ts4 + m * 64 + lane], a1);
            if (three) a2 = mfma16(pa[j], wb4[2 * ts4 + m * 64 + lane], a2);
          }
        }
        // h0 segment: m-steps 16+str+4j, j=0..7 (plain batched)
        {
          vfloat4 v[16];
          ld16h(v, h0 + (size_t)r_ * kH + str * 32 + koct * 8);
#pragma unroll
          for (int j = 0; j < 8; ++j) pa[j] = pack2(v[2*j], v[2*j+1]);
#pragma unroll
          for (int j = 0; j < 8; ++j) {
            const int m = 16 + str + 4 * j;
            a0 = mfma16(pa[j], wb4[m * 64 + lane], a0);
            a1 = mfma16(pa[j], wb4[ts4 + m * 64 + lane], a1);
            if (three) a2 = mfma16(pa[j], wb4[2 * ts4 + m * 64 + lane], a2);
          }
        }
      } else {
        // h0 segment: m = str+4j, j=0..7
        {
          vfloat4 v[16];
          ld16h(v, h0 + (size_t)r_ * kH + str * 32 + koct * 8);
#pragma unroll
          for (int j = 0; j < 8; ++j) pa[j] = pack2(v[2*j], v[2*j+1]);
#pragma unroll
          for (int j = 0; j < 8; ++j) {
            const int m = str + 4 * j;
            a0 = mfma16(pa[j], wb4[m * 64 + lane], a0);
            a1 = mfma16(pa[j], wb4[ts4 + m * 64 + lane], a1);
          }
        }
        // h1 segment: m = 32+str+4j, j=0..7
        {
          vfloat4 v[16];
          ld16h(v, h1 + (size_t)r_ * kH + str * 32 + koct * 8);
#pragma unroll
          for (int j = 0; j < 8; ++j) pa[j] = pack2(v[2*j], v[2*j+1]);
#pragma unroll
          for (int j = 0; j < 8; ++j) {
            const int m = 32 + str + 4 * j;
            a0 = mfma16(pa[j], wb4[m * 64 + lane], a0);
            a1 = mfma16(pa[j], wb4[ts4 + m * 64 + lane], a1);
          }
        }
      }
      // cross-wave K-stripe reduce: 3 sequential rounds through 6 KB LDS
      for (int s2 = 1; s2 < 4; ++s2) {
        if (str == s2) {
          *(floatx4*)&redp[((rt * 3 + 0) * 64 + lane) * 4] = a0;
          *(floatx4*)&redp[((rt * 3 + 1) * 64 + lane) * 4] = a1;
          if (three) *(floatx4*)&redp[((rt * 3 + 2) * 64 + lane) * 4] = a2;
        }
        __syncthreads();
        if (str == 0) {
          a0 += *(const floatx4*)&redp[((rt * 3 + 0) * 64 + lane) * 4];
          a1 += *(const floatx4*)&redp[((rt * 3 + 1) * 64 + lane) * 4];
          if (three) a2 += *(const floatx4*)&redp[((rt * 3 + 2) * 64 + lane) * 4];
        }
        __syncthreads();
      }
      // gate write: str0 waves, coalesced 16-lane col groups (r12-proven C map)
      if (str == 0) {
        const int rb = rt * 16 + koct * 4;
#pragma unroll
        for (int r = 0; r < 4; ++r)
          st_wt(gatesL + (size_t)(rb + r) * kNG + colg0, a0[r] + b0w);
#pragma unroll
        for (int r = 0; r < 4; ++r)
          st_wt(gatesL + (size_t)(rb + r) * kNG + colg1, a1[r] + b1w);
        if (three) {
#pragma unroll
          for (int r = 0; r < 4; ++r)
            st_wt(gatesL + (size_t)(rb + r) * kNG + colg2, a2[r] + b2w);
        }
      }
    }
    gridbar();

    // ========== Phase B (r9 mapping) ==========
    if (bid < 128) {
      if (e < kT) cellB(gates0, h0, creg, nullptr, e);
    } else {
      if (e >= 1) cellB(gates1, h1, creg, out, e - 1);
    }
    gridbar();
  }
}

extern "C" void kernel_launch(void* const* d_in, const int* in_sizes, int n_in,
                              void* d_out, int out_size, void* d_ws, size_t ws_size,
                              hipStream_t stream) {
  const float* x   = (const float*)d_in[0];
  const float* Wl0 = (const float*)d_in[1];
  const float* bl0 = (const float*)d_in[2];
  const float* Wv0 = (const float*)d_in[3];
  const float* bv0 = (const float*)d_in[4];
  const float* Wl1 = (const float*)d_in[5];
  const float* bl1 = (const float*)d_in[6];
  const float* Wv1 = (const float*)d_in[7];
  const float* bv1 = (const float*)d_in[8];
  (void)in_sizes; (void)n_in; (void)out_size; (void)ws_size;

  float* ws = (float*)d_ws;
  ushort_t* wf0 = (ushort_t*)(ws + kOffWF);                 // [4352][1536] fp16
  ushort_t* wf1 = wf0 + (size_t)4352 * 1536;                // [4352][2048] fp16

  {
    int n;
    n = 4096 * 1536 / 8;
    cvt_fp16_kernel<<<(n + 255) / 256, 256, 0, stream>>>(Wl0, wf0, n);
    n = 256 * 1536 / 8;
    cvt_fp16_kernel<<<(n + 255) / 256, 256, 0, stream>>>(
        Wv0, wf0 + (size_t)4096 * 1536, n);
    n = 4096 * 2048 / 8;
    cvt_fp16_kernel<<<(n + 255) / 256, 256, 0, stream>>>(Wl1, wf1, n);
    n = 256 * 2048 / 8;
    cvt_fp16_kernel<<<(n + 255) / 256, 256, 0, stream>>>(
        Wv1, wf1 + (size_t)4096 * 2048, n);
  }

  onlstm_kernel<<<dim3(kNBLK), dim3(kNTHR), 0, stream>>>(
      x, bl0, bv0, bl1, bv1, wf0, wf1, (float*)d_out, ws);
}

// Round 15
// 11120.112 us; speedup vs baseline: 4.0688x; 4.0688x over previous
//
#include <hip/hip_runtime.h>

namespace {
constexpr int kB  = 32;
constexpr int kT  = 1024;
constexpr int kD  = 512;
constexpr int kH  = 1024;
constexpr int kLV = 128;
constexpr int kNG = 4 * kH + 2 * kLV;   // 4352
constexpr int kNBLK = 256;
constexpr int kNTHR = 512;
// ws float offsets
constexpr int kOffH0 = 8192;
constexpr int kOffWF = kOffH0 + 2 * kB * kH + 2 * kB * kNG;  // unchanged (351... safe)
// LDS byte offsets
constexpr int kRedOff = 3 * 1536 * 2 * 16;   // weight region max: 147456 B
constexpr int kIhOff  = kRedOff + 6144;
constexpr int kFhOff  = kIhOff + 512;
constexpr int kSmxOff = kFhOff + 512;
constexpr int kLdsBytes = kSmxOff + 32;      // 154,656 <= 163,840
}

typedef float vfloat4 __attribute__((ext_vector_type(4)));
typedef float floatx4 __attribute__((ext_vector_type(4)));
typedef _Float16 half8_t __attribute__((ext_vector_type(8)));
typedef unsigned short ushort_t;

static __device__ __forceinline__ unsigned ld_flag(const unsigned* p) {
  return __hip_atomic_load(p, __ATOMIC_RELAXED, __HIP_MEMORY_SCOPE_AGENT);
}
static __device__ __forceinline__ void st_flag(unsigned* p, unsigned v) {
  __hip_atomic_store(p, v, __ATOMIC_RELAXED, __HIP_MEMORY_SCOPE_AGENT);
}
static __device__ __forceinline__ float ld_coh(const float* p) {
  return __hip_atomic_load(p, __ATOMIC_RELAXED, __HIP_MEMORY_SCOPE_AGENT);
}
static __device__ __forceinline__ void st_wt(float* p, float v) {
  asm volatile("global_store_dword %0, %1, off sc0 sc1" :: "v"(p), "v"(v) : "memory");
}
static __device__ __forceinline__ void st_wtu(unsigned* p, unsigned v) {
  asm volatile("global_store_dword %0, %1, off sc0 sc1" :: "v"(p), "v"(v) : "memory");
}
// 8 coherent 16B fp16 loads: A-fragments for 8 m-steps, stride 256B.
// Completed INSIDE one asm block (proven pattern r5-r13).
static __device__ __forceinline__ void ld8h(uint4 v[8], const ushort_t* b) {
  asm volatile(
      "global_load_dwordx4 %0, %8, off sc0 sc1\n\t"
      "global_load_dwordx4 %1, %8, off offset:256 sc0 sc1\n\t"
      "global_load_dwordx4 %2, %8, off offset:512 sc0 sc1\n\t"
      "global_load_dwordx4 %3, %8, off offset:768 sc0 sc1\n\t"
      "global_load_dwordx4 %4, %8, off offset:1024 sc0 sc1\n\t"
      "global_load_dwordx4 %5, %8, off offset:1280 sc0 sc1\n\t"
      "global_load_dwordx4 %6, %8, off offset:1536 sc0 sc1\n\t"
      "global_load_dwordx4 %7, %8, off offset:1792 sc0 sc1\n\t"
      "s_waitcnt vmcnt(0)"
      : "=&v"(v[0]), "=&v"(v[1]), "=&v"(v[2]), "=&v"(v[3]),
        "=&v"(v[4]), "=&v"(v[5]), "=&v"(v[6]), "=&v"(v[7])
      : "v"(b)
      : "memory");
}
// two-base variant: h0 and h1 fragments in ONE batch (one L3 round trip)
static __device__ __forceinline__ void ld8h2(uint4 v[8], uint4 w[8],
                                             const ushort_t* b0, const ushort_t* b1) {
  asm volatile(
      "global_load_dwordx4 %0,  %16, off sc0 sc1\n\t"
      "global_load_dwordx4 %1,  %16, off offset:256 sc0 sc1\n\t"
      "global_load_dwordx4 %2,  %16, off offset:512 sc0 sc1\n\t"
      "global_load_dwordx4 %3,  %16, off offset:768 sc0 sc1\n\t"
      "global_load_dwordx4 %4,  %16, off offset:1024 sc0 sc1\n\t"
      "global_load_dwordx4 %5,  %16, off offset:1280 sc0 sc1\n\t"
      "global_load_dwordx4 %6,  %16, off offset:1536 sc0 sc1\n\t"
      "global_load_dwordx4 %7,  %16, off offset:1792 sc0 sc1\n\t"
      "global_load_dwordx4 %8,  %17, off sc0 sc1\n\t"
      "global_load_dwordx4 %9,  %17, off offset:256 sc0 sc1\n\t"
      "global_load_dwordx4 %10, %17, off offset:512 sc0 sc1\n\t"
      "global_load_dwordx4 %11, %17, off offset:768 sc0 sc1\n\t"
      "global_load_dwordx4 %12, %17, off offset:1024 sc0 sc1\n\t"
      "global_load_dwordx4 %13, %17, off offset:1280 sc0 sc1\n\t"
      "global_load_dwordx4 %14, %17, off offset:1536 sc0 sc1\n\t"
      "global_load_dwordx4 %15, %17, off offset:1792 sc0 sc1\n\t"
      "s_waitcnt vmcnt(0)"
      : "=&v"(v[0]), "=&v"(v[1]), "=&v"(v[2]), "=&v"(v[3]),
        "=&v"(v[4]), "=&v"(v[5]), "=&v"(v[6]), "=&v"(v[7]),
        "=&v"(w[0]), "=&v"(w[1]), "=&v"(w[2]), "=&v"(w[3]),
        "=&v"(w[4]), "=&v"(w[5]), "=&v"(w[6]), "=&v"(w[7])
      : "v"(b0), "v"(b1)
      : "memory");
}
static __device__ __forceinline__ unsigned pkrtz(float a, float b) {
  return __builtin_bit_cast(unsigned, __builtin_amdgcn_cvt_pkrtz(a, b));
}
static __device__ __forceinline__ uint4 pack2(vfloat4 a, vfloat4 b) {
  uint4 r;
  r.x = pkrtz(a.x, a.y); r.y = pkrtz(a.z, a.w);
  r.z = pkrtz(b.x, b.y); r.w = pkrtz(b.z, b.w);
  return r;
}
static __device__ __forceinline__ floatx4 mfma16(uint4 a, uint4 b, floatx4 c) {
  return __builtin_amdgcn_mfma_f32_16x16x32_f16(
      __builtin_bit_cast(half8_t, a), __builtin_bit_cast(half8_t, b), c, 0, 0, 0);
}

// -------- fp32 -> fp16 weight conversion (one-time pre-pass) --------
__global__ __launch_bounds__(256) void cvt_fp16_kernel(
    const float* __restrict__ src, ushort_t* __restrict__ dst, int n8) {
  int i = blockIdx.x * 256 + threadIdx.x;
  if (i >= n8) return;
  const vfloat4* s4 = (const vfloat4*)src;
  vfloat4 a = s4[2 * i], b = s4[2 * i + 1];
  typedef _Float16 h8 __attribute__((ext_vector_type(8)));
  h8 o;
  o[0] = (_Float16)a.x; o[1] = (_Float16)a.y;
  o[2] = (_Float16)a.z; o[3] = (_Float16)a.w;
  o[4] = (_Float16)b.x; o[5] = (_Float16)b.y;
  o[6] = (_Float16)b.z; o[7] = (_Float16)b.w;
  ((h8*)dst)[i] = o;
}

__global__ __launch_bounds__(kNTHR, 2) void onlstm_kernel(
    const float* __restrict__ x,
    const float* __restrict__ bl0, const float* __restrict__ bv0,
    const float* __restrict__ bl1, const float* __restrict__ bv1,
    const ushort_t* __restrict__ wf0u, const ushort_t* __restrict__ wf1u,
    float* __restrict__ out, float* __restrict__ ws)
{
  const int tid = threadIdx.x;
  const int bid = blockIdx.x;

  // ---- workspace ----
  unsigned* flags = (unsigned*)ws;
  unsigned* genp  = (unsigned*)ws + 4096;
  ushort_t* h0f = (ushort_t*)(ws + kOffH0);     // [32][1024] fp16
  ushort_t* h1f = h0f + kB * kH;                // [32][1024] fp16
  float* gates0 = ws + kOffH0 + kB * kH;        // (two fp16 bufs = kB*kH floats)
  float* gates1 = gates0 + kB * kNG;

  __shared__ __align__(16) char sb[kLdsBytes];
  uint4* wb4   = (uint4*)sb;                    // weight B-fragments
  float* redp  = (float*)(sb + kRedOff);        // K-stripe reduce
  float* ih_sh = (float*)(sb + kIhOff);
  float* fh_sh = (float*)(sb + kFhOff);
  float* smx   = (float*)(sb + kSmxOff);

  unsigned seq = 0;
  auto gridbar = [&]() {                        // r8-r13-proven flags-only barrier
    ++seq;
    asm volatile("s_waitcnt vmcnt(0)" ::: "memory");
    __syncthreads();
    if (bid == 0) {
      if (tid >= 1 && tid < kNBLK) {
        while (ld_flag(&flags[tid * 16]) != seq) __builtin_amdgcn_s_sleep(2);
      }
      __syncthreads();
      if (tid == 0) st_flag(genp, seq);
    } else {
      if (tid == 0) {
        st_flag(&flags[bid * 16], seq);
        while (ld_flag(genp) != seq) __builtin_amdgcn_s_sleep(2);
      }
      __syncthreads();
    }
    asm volatile("" ::: "memory");
  };

  // ---- A-phase block type ----
  int L, ntile, cb0;
  if (bid < 32)       { L = 0; ntile = 3; cb0 = bid * 48; }
  else if (bid < 120) { L = 0; ntile = 2; cb0 = 1536 + (bid - 32) * 32; }
  else                { L = 1; ntile = 2; cb0 = (bid - 120) * 32; }
  const int K   = L ? 2048 : 1536;
  const int ts4 = K * 2;                        // uint4 per weight tile
  const bool three = (ntile == 3);
  const ushort_t* wf = L ? wf1u : wf0u;
  const float* blp = L ? bl1 : bl0;
  const float* bvp = L ? bv1 : bv0;
  float* gatesL = L ? gates1 : gates0;

  // wave mapping: rt = row-half, str = K-quarter
  const int lane = tid & 63;
  const int rt   = (tid >> 6) & 1;
  const int str  = tid >> 7;
  const int r_   = rt * 16 + (lane & 15);       // batch row (A-frag row)
  const int koct = lane >> 4;                   // k-octet within 32-k window
  const int colg0 = cb0 + (lane & 15);
  const int colg1 = cb0 + 16 + (lane & 15);
  const int colg2 = cb0 + 32 + (lane & 15);

  // ---- one-time: build weight B-fragments in LDS (lane-linear; r12/13-proven) ----
  for (int tt = 0; tt < ntile; ++tt) {
    const int colb = cb0 + tt * 16;
    for (int idx = tid; idx < ts4; idx += kNTHR) {
      int m = idx >> 6, l2 = idx & 63;
      size_t off = (size_t)(colb + (l2 & 15)) * K + m * 32 + 8 * (l2 >> 4);
      wb4[tt * ts4 + idx] = *(const uint4*)(wf + off);
    }
  }
  const float b0w = (colg0 < 4096) ? blp[colg0] : bvp[colg0 - 4096];
  const float b1w = (colg1 < 4096) ? blp[colg1] : bvp[colg1 - 4096];
  const float b2w = three ? ((colg2 < 4096) ? blp[colg2] : bvp[colg2 - 4096]) : 0.f;
  __syncthreads();

  // zero h0f,h1f (64 KB total as uints, write-through)
  { int idx = bid * kNTHR + tid; if (idx < kB * kH) st_wtu((unsigned*)h0f + idx, 0u); }
  float creg = 0.f;
  gridbar();

  // phase-B cell update (r9/r13-proven structure; h stored as fp16 pairs)
  const int pbB  = (bid & 127) >> 2;
  const int qq4B = bid & 3;
  auto cellB = [&](const float* gbase, ushort_t* hb, float& cr, float* outp, int t) {
    const float* gr = gbase + (size_t)pbB * kNG;
    const int wl = tid & 63, wv2 = tid >> 6;
    const bool sm = tid < 128;
    const bool cl = tid < 256;
    float vi = 0.f, vf = 0.f, vo = 0.f, vg = 0.f;
    int j = qq4B * 256 + tid;
    if (cl) {
      vi = ld_coh(gr + j);
      vf = ld_coh(gr + kH + j);
      vo = ld_coh(gr + 2 * kH + j);
      vg = ld_coh(gr + 3 * kH + j);
    }
    float ai = 0.f, af = 0.f;
    if (sm) { ai = ld_coh(gr + 4096 + tid); af = ld_coh(gr + 4096 + kLV + tid); }
    float mi = ai, mf = af;
    if (sm) {
#pragma unroll
      for (int d2 = 32; d2 > 0; d2 >>= 1) {
        mi = fmaxf(mi, __shfl_xor(mi, d2));
        mf = fmaxf(mf, __shfl_xor(mf, d2));
      }
      if (wl == 0) { smx[wv2] = mi; smx[2 + wv2] = mf; }
    }
    __syncthreads();
    mi = fmaxf(smx[0], smx[1]);
    mf = fmaxf(smx[2], smx[3]);
    float ei = 0.f, Pi = 0.f, Pf = 0.f;
    if (sm) {
      ei = __expf(ai - mi);
      float ef = __expf(af - mf);
      Pi = ei; Pf = ef;
#pragma unroll
      for (int d2 = 1; d2 < 64; d2 <<= 1) {
        float ni = __shfl_up(Pi, d2);
        float nf = __shfl_up(Pf, d2);
        if (wl >= d2) { Pi += ni; Pf += nf; }
      }
      if (wl == 63) { smx[4 + wv2] = Pi; smx[6 + wv2] = Pf; }
    }
    __syncthreads();
    float Si = smx[4] + smx[5], Sf = smx[6] + smx[7];
    if (sm) {
      if (wv2 == 1) { Pi += smx[4]; Pf += smx[6]; }
      ih_sh[tid] = Pf / Sf;
      fh_sh[tid] = (Si - Pi + ei) / Si;
    }
    __syncthreads();
    if (cl) {
      float i_ = 1.f / (1.f + __expf(-vi));
      float f_ = 1.f / (1.f + __expf(-vf));
      float o_ = 1.f / (1.f + __expf(-vo));
      float g_ = tanhf(vg);
      int l2 = j >> 3;
      float ih = ih_sh[l2], fh = fh_sh[l2];
      float w  = ih * fh;
      float cold = cr;
      float cn = w * (f_ * cold + i_ * g_) + (fh - w) * cold + (ih - w) * g_;
      float hn = o_ * tanhf(cn);
      cr = cn;
      // fp16 pair store: even lane packs (own, right-neighbor), dword store
      float hnn = __shfl_xor(hn, 1);
      if (!(tid & 1))
        st_wtu((unsigned*)hb + ((size_t)pbB * kH + j) / 2, pkrtz(hn, hnn));
      if (outp) st_wt(outp + ((size_t)pbB * kT + t) * kH + j, hn);
    }
  };

  for (int e = 0; e <= kT; ++e) {
    const bool actA = L ? (e >= 1) : (e < kT);

    // ========== Phase A: MFMA, zero syncs in K loop ==========
    if (actA) {
      floatx4 a0 = {0.f,0.f,0.f,0.f}, a1 = a0, a2 = a0;
      if (L == 0) {
        // x segment: m-steps str+4j, j=0..3 (plain cached loads; x immutable)
        {
          const float* bx = x + ((size_t)r_ * kT + e) * kD + str * 32 + koct * 8;
          vfloat4 vx[8];
#pragma unroll
          for (int j = 0; j < 4; ++j) {
            vx[2*j]   = *(const vfloat4*)(bx + j * 128);
            vx[2*j+1] = *(const vfloat4*)(bx + j * 128 + 4);
          }
          uint4 pa[4];
#pragma unroll
          for (int j = 0; j < 4; ++j) pa[j] = pack2(vx[2*j], vx[2*j+1]);
#pragma unroll
          for (int j = 0; j < 4; ++j) {
            const int m = str + 4 * j;
            a0 = mfma16(pa[j], wb4[m * 64 + lane], a0);
            a1 = mfma16(pa[j], wb4[ts4 + m * 64 + lane], a1);
            if (three) a2 = mfma16(pa[j], wb4[2 * ts4 + m * 64 + lane], a2);
          }
        }
        // h0 segment: fp16 direct A-frags, m = 16+str+4j, j=0..7
        {
          uint4 pa[8];
          ld8h(pa, h0f + (size_t)r_ * kH + str * 32 + koct * 8);
#pragma unroll
          for (int j = 0; j < 8; ++j) {
            const int m = 16 + str + 4 * j;
            a0 = mfma16(pa[j], wb4[m * 64 + lane], a0);
            a1 = mfma16(pa[j], wb4[ts4 + m * 64 + lane], a1);
            if (three) a2 = mfma16(pa[j], wb4[2 * ts4 + m * 64 + lane], a2);
          }
        }
      } else {
        // h0 + h1 fragments in ONE batched load (one L3 round trip)
        uint4 pa[8], pb[8];
        ld8h2(pa, pb, h0f + (size_t)r_ * kH + str * 32 + koct * 8,
                      h1f + (size_t)r_ * kH + str * 32 + koct * 8);
#pragma unroll
        for (int j = 0; j < 8; ++j) {
          const int m = str + 4 * j;
          a0 = mfma16(pa[j], wb4[m * 64 + lane], a0);
          a1 = mfma16(pa[j], wb4[ts4 + m * 64 + lane], a1);
        }
#pragma unroll
        for (int j = 0; j < 8; ++j) {
          const int m = 32 + str + 4 * j;
          a0 = mfma16(pb[j], wb4[m * 64 + lane], a0);
          a1 = mfma16(pb[j], wb4[ts4 + m * 64 + lane], a1);
        }
      }
      // cross-wave K-stripe reduce: 3 sequential rounds through 6 KB LDS
      for (int s2 = 1; s2 < 4; ++s2) {
        if (str == s2) {
          *(floatx4*)&redp[((rt * 3 + 0) * 64 + lane) * 4] = a0;
          *(floatx4*)&redp[((rt * 3 + 1) * 64 + lane) * 4] = a1;
          if (three) *(floatx4*)&redp[((rt * 3 + 2) * 64 + lane) * 4] = a2;
        }
        __syncthreads();
        if (str == 0) {
          a0 += *(const floatx4*)&redp[((rt * 3 + 0) * 64 + lane) * 4];
          a1 += *(const floatx4*)&redp[((rt * 3 + 1) * 64 + lane) * 4];
          if (three) a2 += *(const floatx4*)&redp[((rt * 3 + 2) * 64 + lane) * 4];
        }
        __syncthreads();
      }
      // gate write: str0 waves, coalesced 16-lane col groups (r12/13-proven C map)
      if (str == 0) {
        const int rb = rt * 16 + koct * 4;
#pragma unroll
        for (int r = 0; r < 4; ++r)
          st_wt(gatesL + (size_t)(rb + r) * kNG + colg0, a0[r] + b0w);
#pragma unroll
        for (int r = 0; r < 4; ++r)
          st_wt(gatesL + (size_t)(rb + r) * kNG + colg1, a1[r] + b1w);
        if (three) {
#pragma unroll
          for (int r = 0; r < 4; ++r)
            st_wt(gatesL + (size_t)(rb + r) * kNG + colg2, a2[r] + b2w);
        }
      }
    }
    gridbar();

    // ========== Phase B (r9/r13 mapping) ==========
    if (bid < 128) {
      if (e < kT) cellB(gates0, h0f, creg, nullptr, e);
    } else {
      if (e >= 1) cellB(gates1, h1f, creg, out, e - 1);
    }
    gridbar();
  }
}

extern "C" void kernel_launch(void* const* d_in, const int* in_sizes, int n_in,
                              void* d_out, int out_size, void* d_ws, size_t ws_size,
                              hipStream_t stream) {
  const float* x   = (const float*)d_in[0];
  const float* Wl0 = (const float*)d_in[1];
  const float* bl0 = (const float*)d_in[2];
  const float* Wv0 = (const float*)d_in[3];
  const float* bv0 = (const float*)d_in[4];
  const float* Wl1 = (const float*)d_in[5];
  const float* bl1 = (const float*)d_in[6];
  const float* Wv1 = (const float*)d_in[7];
  const float* bv1 = (const float*)d_in[8];
  (void)in_sizes; (void)n_in; (void)out_size; (void)ws_size;

  float* ws = (float*)d_ws;
  ushort_t* wf0 = (ushort_t*)(ws + kOffWF);                 // [4352][1536] fp16
  ushort_t* wf1 = wf0 + (size_t)4352 * 1536;                // [4352][2048] fp16

  {
    int n;
    n = 4096 * 1536 / 8;
    cvt_fp16_kernel<<<(n + 255) / 256, 256, 0, stream>>>(Wl0, wf0, n);
    n = 256 * 1536 / 8;
    cvt_fp16_kernel<<<(n + 255) / 256, 256, 0, stream>>>(
        Wv0, wf0 + (size_t)4096 * 1536, n);
    n = 4096 * 2048 / 8;
    cvt_fp16_kernel<<<(n + 255) / 256, 256, 0, stream>>>(Wl1, wf1, n);
    n = 256 * 2048 / 8;
    cvt_fp16_kernel<<<(n + 255) / 256, 256, 0, stream>>>(
        Wv1, wf1 + (size_t)4096 * 2048, n);
  }

  onlstm_kernel<<<dim3(kNBLK), dim3(kNTHR), 0, stream>>>(
      x, bl0, bv0, bl1, bv1, wf0, wf1, (float*)d_out, ws);
}

// Round 16
// 10879.572 us; speedup vs baseline: 4.1588x; 1.0221x over previous
//
#include <hip/hip_runtime.h>

namespace {
constexpr int kB  = 32;
constexpr int kT  = 1024;
constexpr int kD  = 512;
constexpr int kH  = 1024;
constexpr int kLV = 128;
constexpr int kNG = 4 * kH + 2 * kLV;   // 4352
constexpr int kNBLK = 256;
constexpr int kNTHR = 512;
// ws float offsets: flagA = uints[0..4095], flagB = uints[4096..8191]
constexpr int kOffH0 = 8192;
constexpr int kOffWF = kOffH0 + 2 * kB * kH + 2 * kB * kNG;
// LDS byte offsets
constexpr int kRedOff = 3 * 1536 * 2 * 16;   // weight region max: 147456 B
constexpr int kIhOff  = kRedOff + 12288;     // red: 12 slots x 64 lanes x 16B
constexpr int kFhOff  = kIhOff + 512;
constexpr int kSmxOff = kFhOff + 512;
constexpr int kLdsBytes = kSmxOff + 32;      // 160,800 <= 163,840
}

typedef float vfloat4 __attribute__((ext_vector_type(4)));
typedef float floatx4 __attribute__((ext_vector_type(4)));
typedef _Float16 half8_t __attribute__((ext_vector_type(8)));
typedef unsigned short ushort_t;

static __device__ __forceinline__ unsigned ld_flag(const unsigned* p) {
  return __hip_atomic_load(p, __ATOMIC_RELAXED, __HIP_MEMORY_SCOPE_AGENT);
}
static __device__ __forceinline__ void st_flag(unsigned* p, unsigned v) {
  __hip_atomic_store(p, v, __ATOMIC_RELAXED, __HIP_MEMORY_SCOPE_AGENT);
}
static __device__ __forceinline__ float ld_coh(const float* p) {
  return __hip_atomic_load(p, __ATOMIC_RELAXED, __HIP_MEMORY_SCOPE_AGENT);
}
static __device__ __forceinline__ void st_wt(float* p, float v) {
  asm volatile("global_store_dword %0, %1, off sc0 sc1" :: "v"(p), "v"(v) : "memory");
}
static __device__ __forceinline__ void st_wtu(unsigned* p, unsigned v) {
  asm volatile("global_store_dword %0, %1, off sc0 sc1" :: "v"(p), "v"(v) : "memory");
}
// 8 coherent 16B fp16 loads, completed INSIDE one asm block (proven r5-r15).
static __device__ __forceinline__ void ld8h(uint4 v[8], const ushort_t* b) {
  asm volatile(
      "global_load_dwordx4 %0, %8, off sc0 sc1\n\t"
      "global_load_dwordx4 %1, %8, off offset:256 sc0 sc1\n\t"
      "global_load_dwordx4 %2, %8, off offset:512 sc0 sc1\n\t"
      "global_load_dwordx4 %3, %8, off offset:768 sc0 sc1\n\t"
      "global_load_dwordx4 %4, %8, off offset:1024 sc0 sc1\n\t"
      "global_load_dwordx4 %5, %8, off offset:1280 sc0 sc1\n\t"
      "global_load_dwordx4 %6, %8, off offset:1536 sc0 sc1\n\t"
      "global_load_dwordx4 %7, %8, off offset:1792 sc0 sc1\n\t"
      "s_waitcnt vmcnt(0)"
      : "=&v"(v[0]), "=&v"(v[1]), "=&v"(v[2]), "=&v"(v[3]),
        "=&v"(v[4]), "=&v"(v[5]), "=&v"(v[6]), "=&v"(v[7])
      : "v"(b)
      : "memory");
}
// two-base variant: h0 and h1 fragments in ONE batch (one L3 round trip)
static __device__ __forceinline__ void ld8h2(uint4 v[8], uint4 w[8],
                                             const ushort_t* b0, const ushort_t* b1) {
  asm volatile(
      "global_load_dwordx4 %0,  %16, off sc0 sc1\n\t"
      "global_load_dwordx4 %1,  %16, off offset:256 sc0 sc1\n\t"
      "global_load_dwordx4 %2,  %16, off offset:512 sc0 sc1\n\t"
      "global_load_dwordx4 %3,  %16, off offset:768 sc0 sc1\n\t"
      "global_load_dwordx4 %4,  %16, off offset:1024 sc0 sc1\n\t"
      "global_load_dwordx4 %5,  %16, off offset:1280 sc0 sc1\n\t"
      "global_load_dwordx4 %6,  %16, off offset:1536 sc0 sc1\n\t"
      "global_load_dwordx4 %7,  %16, off offset:1792 sc0 sc1\n\t"
      "global_load_dwordx4 %8,  %17, off sc0 sc1\n\t"
      "global_load_dwordx4 %9,  %17, off offset:256 sc0 sc1\n\t"
      "global_load_dwordx4 %10, %17, off offset:512 sc0 sc1\n\t"
      "global_load_dwordx4 %11, %17, off offset:768 sc0 sc1\n\t"
      "global_load_dwordx4 %12, %17, off offset:1024 sc0 sc1\n\t"
      "global_load_dwordx4 %13, %17, off offset:1280 sc0 sc1\n\t"
      "global_load_dwordx4 %14, %17, off offset:1536 sc0 sc1\n\t"
      "global_load_dwordx4 %15, %17, off offset:1792 sc0 sc1\n\t"
      "s_waitcnt vmcnt(0)"
      : "=&v"(v[0]), "=&v"(v[1]), "=&v"(v[2]), "=&v"(v[3]),
        "=&v"(v[4]), "=&v"(v[5]), "=&v"(v[6]), "=&v"(v[7]),
        "=&v"(w[0]), "=&v"(w[1]), "=&v"(w[2]), "=&v"(w[3]),
        "=&v"(w[4]), "=&v"(w[5]), "=&v"(w[6]), "=&v"(w[7])
      : "v"(b0), "v"(b1)
      : "memory");
}
static __device__ __forceinline__ unsigned pkrtz(float a, float b) {
  return __builtin_bit_cast(unsigned, __builtin_amdgcn_cvt_pkrtz(a, b));
}
static __device__ __forceinline__ uint4 pack2(vfloat4 a, vfloat4 b) {
  uint4 r;
  r.x = pkrtz(a.x, a.y); r.y = pkrtz(a.z, a.w);
  r.z = pkrtz(b.x, b.y); r.w = pkrtz(b.z, b.w);
  return r;
}
static __device__ __forceinline__ floatx4 mfma16(uint4 a, uint4 b, floatx4 c) {
  return __builtin_amdgcn_mfma_f32_16x16x32_f16(
      __builtin_bit_cast(half8_t, a), __builtin_bit_cast(half8_t, b), c, 0, 0, 0);
}

// -------- fp32 -> fp16 weight conversion (one-time pre-pass) --------
__global__ __launch_bounds__(256) void cvt_fp16_kernel(
    const float* __restrict__ src, ushort_t* __restrict__ dst, int n8) {
  int i = blockIdx.x * 256 + threadIdx.x;
  if (i >= n8) return;
  const vfloat4* s4 = (const vfloat4*)src;
  vfloat4 a = s4[2 * i], b = s4[2 * i + 1];
  typedef _Float16 h8 __attribute__((ext_vector_type(8)));
  h8 o;
  o[0] = (_Float16)a.x; o[1] = (_Float16)a.y;
  o[2] = (_Float16)a.z; o[3] = (_Float16)a.w;
  o[4] = (_Float16)b.x; o[5] = (_Float16)b.y;
  o[6] = (_Float16)b.z; o[7] = (_Float16)b.w;
  ((h8*)dst)[i] = o;
}

__global__ __launch_bounds__(kNTHR, 2) void onlstm_kernel(
    const float* __restrict__ x,
    const float* __restrict__ bl0, const float* __restrict__ bv0,
    const float* __restrict__ bl1, const float* __restrict__ bv1,
    const ushort_t* __restrict__ wf0u, const ushort_t* __restrict__ wf1u,
    float* __restrict__ out, float* __restrict__ ws)
{
  const int tid = threadIdx.x;
  const int bid = blockIdx.x;

  // ---- workspace ----
  unsigned* flagA = (unsigned*)ws;              // [256] stride-16 uints
  unsigned* flagB = (unsigned*)ws + 4096;       // [256] stride-16 uints
  ushort_t* h0f = (ushort_t*)(ws + kOffH0);     // [32][1024] fp16
  ushort_t* h1f = h0f + kB * kH;                // [32][1024] fp16
  float* gates0 = ws + kOffH0 + kB * kH;
  float* gates1 = gates0 + kB * kNG;

  __shared__ __align__(16) char sb[kLdsBytes];
  uint4* wb4   = (uint4*)sb;                    // weight B-fragments
  float* redp  = (float*)(sb + kRedOff);        // K-stripe reduce (12 KB)
  float* ih_sh = (float*)(sb + kIhOff);
  float* fh_sh = (float*)(sb + kFhOff);
  float* smx   = (float*)(sb + kSmxOff);

  // signal: drain own stores, block-wide rendezvous, tid0 publishes flag
  auto signal = [&](unsigned* arr, unsigned v) {
    asm volatile("s_waitcnt vmcnt(0)" ::: "memory");
    __syncthreads();
    if (tid == 0) st_flag(&arr[bid * 16], v);
  };
  // wait: thread i polls flag lo+i until == target (equality safe: overrun
  // impossible — every flag's waiter-set is a subset of its owner's next
  // wait-set; monotone rewrite handles replay-stale values / 0xAA poison)
  auto wait_set = [&](unsigned* arr, int lo, int n, unsigned target) {
    if (tid < n) {
      while (ld_flag(&arr[(lo + tid) * 16]) != target)
        __builtin_amdgcn_s_sleep(2);
    }
    __syncthreads();
    asm volatile("" ::: "memory");
  };

  // ---- A-phase block type ----
  int L, ntile, cb0;
  if (bid < 32)       { L = 0; ntile = 3; cb0 = bid * 48; }
  else if (bid < 120) { L = 0; ntile = 2; cb0 = 1536 + (bid - 32) * 32; }
  else                { L = 1; ntile = 2; cb0 = (bid - 120) * 32; }
  const int K   = L ? 2048 : 1536;
  const int ts4 = K * 2;                        // uint4 per weight tile
  const bool three = (ntile == 3);
  const int rstride = three ? 3 : 2;
  const ushort_t* wf = L ? wf1u : wf0u;
  const float* blp = L ? bl1 : bl0;
  const float* bvp = L ? bv1 : bv0;
  float* gatesL = L ? gates1 : gates0;

  // wave mapping: rt = row-half, str = K-quarter
  const int lane = tid & 63;
  const int rt   = (tid >> 6) & 1;
  const int str  = tid >> 7;
  const int r_   = rt * 16 + (lane & 15);
  const int koct = lane >> 4;
  const int colg0 = cb0 + (lane & 15);
  const int colg1 = cb0 + 16 + (lane & 15);
  const int colg2 = cb0 + 32 + (lane & 15);

  // red slot address: slot x rt x accIdx x 64 lanes x 16B
  auto redsl = [&](int slot, int accIdx) -> float* {
    return &redp[(((slot * 2 + rt) * rstride) + accIdx) * 256 + lane * 4];
  };

  // ---- one-time: build weight B-fragments in LDS (lane-linear; r12+-proven) ----
  for (int tt = 0; tt < ntile; ++tt) {
    const int colb = cb0 + tt * 16;
    for (int idx = tid; idx < ts4; idx += kNTHR) {
      int m = idx >> 6, l2 = idx & 63;
      size_t off = (size_t)(colb + (l2 & 15)) * K + m * 32 + 8 * (l2 >> 4);
      wb4[tt * ts4 + idx] = *(const uint4*)(wf + off);
    }
  }
  const float b0w = (colg0 < 4096) ? blp[colg0] : bvp[colg0 - 4096];
  const float b1w = (colg1 < 4096) ? blp[colg1] : bvp[colg1 - 4096];
  const float b2w = three ? ((colg2 < 4096) ? blp[colg2] : bvp[colg2 - 4096]) : 0.f;
  __syncthreads();

  // zero h0f,h1f (128 KB as dwords, write-through), signal as "B of epoch -1"
  { int idx = bid * kNTHR + tid; if (idx < kB * kH) st_wtu((unsigned*)h0f + idx, 0u); }
  float creg = 0.f;
  signal(flagB, 1u);
  if (bid < 120) wait_set(flagB, 0, 128, 1u);
  else           wait_set(flagB, 0, 256, 1u);

  // phase-B cell update (r9/r13/r15-proven)
  const int pbB  = (bid & 127) >> 2;
  const int qq4B = bid & 3;
  auto cellB = [&](const float* gbase, ushort_t* hb, float& cr, float* outp, int t) {
    const float* gr = gbase + (size_t)pbB * kNG;
    const int wl = tid & 63, wv2 = tid >> 6;
    const bool sm = tid < 128;
    const bool cl = tid < 256;
    float vi = 0.f, vf = 0.f, vo = 0.f, vg = 0.f;
    int j = qq4B * 256 + tid;
    if (cl) {
      vi = ld_coh(gr + j);
      vf = ld_coh(gr + kH + j);
      vo = ld_coh(gr + 2 * kH + j);
      vg = ld_coh(gr + 3 * kH + j);
    }
    float ai = 0.f, af = 0.f;
    if (sm) { ai = ld_coh(gr + 4096 + tid); af = ld_coh(gr + 4096 + kLV + tid); }
    float mi = ai, mf = af;
    if (sm) {
#pragma unroll
      for (int d2 = 32; d2 > 0; d2 >>= 1) {
        mi = fmaxf(mi, __shfl_xor(mi, d2));
        mf = fmaxf(mf, __shfl_xor(mf, d2));
      }
      if (wl == 0) { smx[wv2] = mi; smx[2 + wv2] = mf; }
    }
    __syncthreads();
    mi = fmaxf(smx[0], smx[1]);
    mf = fmaxf(smx[2], smx[3]);
    float ei = 0.f, Pi = 0.f, Pf = 0.f;
    if (sm) {
      ei = __expf(ai - mi);
      float ef = __expf(af - mf);
      Pi = ei; Pf = ef;
#pragma unroll
      for (int d2 = 1; d2 < 64; d2 <<= 1) {
        float ni = __shfl_up(Pi, d2);
        float nf = __shfl_up(Pf, d2);
        if (wl >= d2) { Pi += ni; Pf += nf; }
      }
      if (wl == 63) { smx[4 + wv2] = Pi; smx[6 + wv2] = Pf; }
    }
    __syncthreads();
    float Si = smx[4] + smx[5], Sf = smx[6] + smx[7];
    if (sm) {
      if (wv2 == 1) { Pi += smx[4]; Pf += smx[6]; }
      ih_sh[tid] = Pf / Sf;
      fh_sh[tid] = (Si - Pi + ei) / Si;
    }
    __syncthreads();
    if (cl) {
      float i_ = 1.f / (1.f + __expf(-vi));
      float f_ = 1.f / (1.f + __expf(-vf));
      float o_ = 1.f / (1.f + __expf(-vo));
      float g_ = tanhf(vg);
      int l2 = j >> 3;
      float ih = ih_sh[l2], fh = fh_sh[l2];
      float w  = ih * fh;
      float cold = cr;
      float cn = w * (f_ * cold + i_ * g_) + (fh - w) * cold + (ih - w) * g_;
      float hn = o_ * tanhf(cn);
      cr = cn;
      float hnn = __shfl_xor(hn, 1);
      if (!(tid & 1))
        st_wtu((unsigned*)hb + ((size_t)pbB * kH + j) / 2, pkrtz(hn, hnn));
      if (outp) st_wt(outp + ((size_t)pbB * kT + t) * kH + j, hn);
    }
  };

  for (int e = 0; e <= kT; ++e) {
    const bool actA = L ? (e >= 1) : (e < kT);

    // ========== Phase A: MFMA, zero syncs in K loop ==========
    if (actA) {
      floatx4 a0 = {0.f,0.f,0.f,0.f}, a1 = a0, a2 = a0;
      if (L == 0) {
        {
          const float* bx = x + ((size_t)r_ * kT + e) * kD + str * 32 + koct * 8;
          vfloat4 vx[8];
#pragma unroll
          for (int j = 0; j < 4; ++j) {
            vx[2*j]   = *(const vfloat4*)(bx + j * 128);
            vx[2*j+1] = *(const vfloat4*)(bx + j * 128 + 4);
          }
          uint4 pa[4];
#pragma unroll
          for (int j = 0; j < 4; ++j) pa[j] = pack2(vx[2*j], vx[2*j+1]);
#pragma unroll
          for (int j = 0; j < 4; ++j) {
            const int m = str + 4 * j;
            a0 = mfma16(pa[j], wb4[m * 64 + lane], a0);
            a1 = mfma16(pa[j], wb4[ts4 + m * 64 + lane], a1);
            if (three) a2 = mfma16(pa[j], wb4[2 * ts4 + m * 64 + lane], a2);
          }
        }
        {
          uint4 pa[8];
          ld8h(pa, h0f + (size_t)r_ * kH + str * 32 + koct * 8);
#pragma unroll
          for (int j = 0; j < 8; ++j) {
            const int m = 16 + str + 4 * j;
            a0 = mfma16(pa[j], wb4[m * 64 + lane], a0);
            a1 = mfma16(pa[j], wb4[ts4 + m * 64 + lane], a1);
            if (three) a2 = mfma16(pa[j], wb4[2 * ts4 + m * 64 + lane], a2);
          }
        }
      } else {
        uint4 pa[8], pb[8];
        ld8h2(pa, pb, h0f + (size_t)r_ * kH + str * 32 + koct * 8,
                      h1f + (size_t)r_ * kH + str * 32 + koct * 8);
#pragma unroll
        for (int j = 0; j < 8; ++j) {
          const int m = str + 4 * j;
          a0 = mfma16(pa[j], wb4[m * 64 + lane], a0);
          a1 = mfma16(pa[j], wb4[ts4 + m * 64 + lane], a1);
        }
#pragma unroll
        for (int j = 0; j < 8; ++j) {
          const int m = 32 + str + 4 * j;
          a0 = mfma16(pb[j], wb4[m * 64 + lane], a0);
          a1 = mfma16(pb[j], wb4[ts4 + m * 64 + lane], a1);
        }
      }
      // K-stripe reduce: 2-tile one-shot (1 sync); 3-tile two-round (3 syncs)
      if (!three) {
        if (str != 0) {
          *(floatx4*)redsl(str - 1, 0) = a0;
          *(floatx4*)redsl(str - 1, 1) = a1;
        }
        __syncthreads();
        if (str == 0) {
#pragma unroll
          for (int s2 = 0; s2 < 3; ++s2) {
            a0 += *(const floatx4*)redsl(s2, 0);
            a1 += *(const floatx4*)redsl(s2, 1);
          }
        }
      } else {
        if (str == 1 || str == 2) {
          *(floatx4*)redsl(str - 1, 0) = a0;
          *(floatx4*)redsl(str - 1, 1) = a1;
          *(floatx4*)redsl(str - 1, 2) = a2;
        }
        __syncthreads();
        if (str == 0) {
#pragma unroll
          for (int s2 = 0; s2 < 2; ++s2) {
            a0 += *(const floatx4*)redsl(s2, 0);
            a1 += *(const floatx4*)redsl(s2, 1);
            a2 += *(const floatx4*)redsl(s2, 2);
          }
        }
        __syncthreads();
        if (str == 3) {
          *(floatx4*)redsl(0, 0) = a0;
          *(floatx4*)redsl(0, 1) = a1;
          *(floatx4*)redsl(0, 2) = a2;
        }
        __syncthreads();
        if (str == 0) {
          a0 += *(const floatx4*)redsl(0, 0);
          a1 += *(const floatx4*)redsl(0, 1);
          a2 += *(const floatx4*)redsl(0, 2);
        }
      }
      // gate write: str0 waves, coalesced 16-lane col groups
      if (str == 0) {
        const int rb = rt * 16 + koct * 4;
#pragma unroll
        for (int r = 0; r < 4; ++r)
          st_wt(gatesL + (size_t)(rb + r) * kNG + colg0, a0[r] + b0w);
#pragma unroll
        for (int r = 0; r < 4; ++r)
          st_wt(gatesL + (size_t)(rb + r) * kNG + colg1, a1[r] + b1w);
        if (three) {
#pragma unroll
          for (int r = 0; r < 4; ++r)
            st_wt(gatesL + (size_t)(rb + r) * kNG + colg2, a2[r] + b2w);
        }
      }
    }
    // ---- signal A done; wait for B-part dependencies ----
    signal(flagA, (unsigned)(e + 1));
    if (bid < 128) wait_set(flagA, 0, 256, (unsigned)(e + 1));      // L0-B: h0 readers = all A
    else           wait_set(flagA, 120, 136, (unsigned)(e + 1));    // L1-B: gates1 + h1 readers

    // ========== Phase B ==========
    if (bid < 128) {
      if (e < kT) cellB(gates0, h0f, creg, nullptr, e);
    } else {
      if (e >= 1) cellB(gates1, h1f, creg, out, e - 1);
    }
    // ---- signal B done; wait for next-A dependencies ----
    signal(flagB, (unsigned)(e + 2));
    if (e < kT) {
      if (bid < 120) wait_set(flagB, 0, 128, (unsigned)(e + 2));    // L0-A: h0 writers
      else           wait_set(flagB, 0, 256, (unsigned)(e + 2));    // L1-A: h0+h1 writers
    }
  }
}

extern "C" void kernel_launch(void* const* d_in, const int* in_sizes, int n_in,
                              void* d_out, int out_size, void* d_ws, size_t ws_size,
                              hipStream_t stream) {
  const float* x   = (const float*)d_in[0];
  const float* Wl0 = (const float*)d_in[1];
  const float* bl0 = (const float*)d_in[2];
  const float* Wv0 = (const float*)d_in[3];
  const float* bv0 = (const float*)d_in[4];
  const float* Wl1 = (const float*)d_in[5];
  const float* bl1 = (const float*)d_in[6];
  const float* Wv1 = (const float*)d_in[7];
  const float* bv1 = (const float*)d_in[8];
  (void)in_sizes; (void)n_in; (void)out_size; (void)ws_size;

  float* ws = (float*)d_ws;
  ushort_t* wf0 = (ushort_t*)(ws + kOffWF);                 // [4352][1536] fp16
  ushort_t* wf1 = wf0 + (size_t)4352 * 1536;                // [4352][2048] fp16

  {
    int n;
    n = 4096 * 1536 / 8;
    cvt_fp16_kernel<<<(n + 255) / 256, 256, 0, stream>>>(Wl0, wf0, n);
    n = 256 * 1536 / 8;
    cvt_fp16_kernel<<<(n + 255) / 256, 256, 0, stream>>>(
        Wv0, wf0 + (size_t)4096 * 1536, n);
    n = 4096 * 2048 / 8;
    cvt_fp16_kernel<<<(n + 255) / 256, 256, 0, stream>>>(Wl1, wf1, n);
    n = 256 * 2048 / 8;
    cvt_fp16_kernel<<<(n + 255) / 256, 256, 0, stream>>>(
        Wv1, wf1 + (size_t)4096 * 2048, n);
  }

  onlstm_kernel<<<dim3(kNBLK), dim3(kNTHR), 0, stream>>>(
      x, bl0, bv0, bl1, bv1, wf0, wf1, (float*)d_out, ws);
}

// Round 17
// 9912.285 us; speedup vs baseline: 4.5646x; 1.0976x over previous
//
#include <hip/hip_runtime.h>

namespace {
constexpr int kB  = 32;
constexpr int kT  = 1024;
constexpr int kD  = 512;
constexpr int kH  = 1024;
constexpr int kLV = 128;
constexpr int kNG = 4 * kH + 2 * kLV;   // 4352
constexpr int kNBLK = 256;
constexpr int kNTHR = 512;
// ws uint offsets: flagA[0..4095], flagB[4096..8191], cflags[8192..12287], cgenp[12288]
constexpr int kOffH0 = 16384;           // float offset of h region
// LDS byte offsets
constexpr int kRedOff = 3 * 1536 * 2 * 16;   // weight region max: 147456 B
constexpr int kIhOff  = kRedOff + 12288;
constexpr int kFhOff  = kIhOff + 512;
constexpr int kLdsBytes = kFhOff + 512;      // 160,768 <= 163,840
}

typedef float vfloat4 __attribute__((ext_vector_type(4)));
typedef float floatx4 __attribute__((ext_vector_type(4)));
typedef _Float16 half8_t __attribute__((ext_vector_type(8)));
typedef unsigned short ushort_t;

static __device__ __forceinline__ unsigned ld_flag(const unsigned* p) {
  return __hip_atomic_load(p, __ATOMIC_RELAXED, __HIP_MEMORY_SCOPE_AGENT);
}
static __device__ __forceinline__ void st_flag(unsigned* p, unsigned v) {
  __hip_atomic_store(p, v, __ATOMIC_RELAXED, __HIP_MEMORY_SCOPE_AGENT);
}
static __device__ __forceinline__ float ld_coh(const float* p) {
  return __hip_atomic_load(p, __ATOMIC_RELAXED, __HIP_MEMORY_SCOPE_AGENT);
}
static __device__ __forceinline__ void st_wt(float* p, float v) {
  asm volatile("global_store_dword %0, %1, off sc0 sc1" :: "v"(p), "v"(v) : "memory");
}
static __device__ __forceinline__ void st_wtu(unsigned* p, unsigned v) {
  asm volatile("global_store_dword %0, %1, off sc0 sc1" :: "v"(p), "v"(v) : "memory");
}
// 8 coherent 16B fp16 loads, completed INSIDE one asm block (proven r5-r16).
static __device__ __forceinline__ void ld8h(uint4 v[8], const ushort_t* b) {
  asm volatile(
      "global_load_dwordx4 %0, %8, off sc0 sc1\n\t"
      "global_load_dwordx4 %1, %8, off offset:256 sc0 sc1\n\t"
      "global_load_dwordx4 %2, %8, off offset:512 sc0 sc1\n\t"
      "global_load_dwordx4 %3, %8, off offset:768 sc0 sc1\n\t"
      "global_load_dwordx4 %4, %8, off offset:1024 sc0 sc1\n\t"
      "global_load_dwordx4 %5, %8, off offset:1280 sc0 sc1\n\t"
      "global_load_dwordx4 %6, %8, off offset:1536 sc0 sc1\n\t"
      "global_load_dwordx4 %7, %8, off offset:1792 sc0 sc1\n\t"
      "s_waitcnt vmcnt(0)"
      : "=&v"(v[0]), "=&v"(v[1]), "=&v"(v[2]), "=&v"(v[3]),
        "=&v"(v[4]), "=&v"(v[5]), "=&v"(v[6]), "=&v"(v[7])
      : "v"(b)
      : "memory");
}
static __device__ __forceinline__ void ld8h2(uint4 v[8], uint4 w[8],
                                             const ushort_t* b0, const ushort_t* b1) {
  asm volatile(
      "global_load_dwordx4 %0,  %16, off sc0 sc1\n\t"
      "global_load_dwordx4 %1,  %16, off offset:256 sc0 sc1\n\t"
      "global_load_dwordx4 %2,  %16, off offset:512 sc0 sc1\n\t"
      "global_load_dwordx4 %3,  %16, off offset:768 sc0 sc1\n\t"
      "global_load_dwordx4 %4,  %16, off offset:1024 sc0 sc1\n\t"
      "global_load_dwordx4 %5,  %16, off offset:1280 sc0 sc1\n\t"
      "global_load_dwordx4 %6,  %16, off offset:1536 sc0 sc1\n\t"
      "global_load_dwordx4 %7,  %16, off offset:1792 sc0 sc1\n\t"
      "global_load_dwordx4 %8,  %17, off sc0 sc1\n\t"
      "global_load_dwordx4 %9,  %17, off offset:256 sc0 sc1\n\t"
      "global_load_dwordx4 %10, %17, off offset:512 sc0 sc1\n\t"
      "global_load_dwordx4 %11, %17, off offset:768 sc0 sc1\n\t"
      "global_load_dwordx4 %12, %17, off offset:1024 sc0 sc1\n\t"
      "global_load_dwordx4 %13, %17, off offset:1280 sc0 sc1\n\t"
      "global_load_dwordx4 %14, %17, off offset:1536 sc0 sc1\n\t"
      "global_load_dwordx4 %15, %17, off offset:1792 sc0 sc1\n\t"
      "s_waitcnt vmcnt(0)"
      : "=&v"(v[0]), "=&v"(v[1]), "=&v"(v[2]), "=&v"(v[3]),
        "=&v"(v[4]), "=&v"(v[5]), "=&v"(v[6]), "=&v"(v[7]),
        "=&v"(w[0]), "=&v"(w[1]), "=&v"(w[2]), "=&v"(w[3]),
        "=&v"(w[4]), "=&v"(w[5]), "=&v"(w[6]), "=&v"(w[7])
      : "v"(b0), "v"(b1)
      : "memory");
}
static __device__ __forceinline__ unsigned pkrtz(float a, float b) {
  return __builtin_bit_cast(unsigned, __builtin_amdgcn_cvt_pkrtz(a, b));
}
static __device__ __forceinline__ uint4 pack2(vfloat4 a, vfloat4 b) {
  uint4 r;
  r.x = pkrtz(a.x, a.y); r.y = pkrtz(a.z, a.w);
  r.z = pkrtz(b.x, b.y); r.w = pkrtz(b.z, b.w);
  return r;
}
static __device__ __forceinline__ floatx4 mfma16(uint4 a, uint4 b, floatx4 c) {
  return __builtin_amdgcn_mfma_f32_16x16x32_f16(
      __builtin_bit_cast(half8_t, a), __builtin_bit_cast(half8_t, b), c, 0, 0, 0);
}

// -------- fp32 -> fp16 weight conversion (one-time pre-pass) --------
__global__ __launch_bounds__(256) void cvt_fp16_kernel(
    const float* __restrict__ src, ushort_t* __restrict__ dst, int n8) {
  int i = blockIdx.x * 256 + threadIdx.x;
  if (i >= n8) return;
  const vfloat4* s4 = (const vfloat4*)src;
  vfloat4 a = s4[2 * i], b = s4[2 * i + 1];
  typedef _Float16 h8 __attribute__((ext_vector_type(8)));
  h8 o;
  o[0] = (_Float16)a.x; o[1] = (_Float16)a.y;
  o[2] = (_Float16)a.z; o[3] = (_Float16)a.w;
  o[4] = (_Float16)b.x; o[5] = (_Float16)b.y;
  o[6] = (_Float16)b.z; o[7] = (_Float16)b.w;
  ((h8*)dst)[i] = o;
}

__global__ __launch_bounds__(kNTHR, 2) void onlstm_kernel(
    const float* __restrict__ x,
    const float* __restrict__ bl0, const float* __restrict__ bv0,
    const float* __restrict__ bl1, const float* __restrict__ bv1,
    const ushort_t* __restrict__ wf0u, const ushort_t* __restrict__ wf1u,
    float* __restrict__ out, float* __restrict__ ws)
{
  const int tid = threadIdx.x;
  const int bid = blockIdx.x;

  // ---- workspace ----
  unsigned* flagA  = (unsigned*)ws;             // [256] stride-16
  unsigned* flagB  = (unsigned*)ws + 4096;      // [256] stride-16
  unsigned* cflags = (unsigned*)ws + 8192;      // init-barrier flags
  unsigned* cgenp  = (unsigned*)ws + 12288;     // init-barrier generation
  ushort_t* h0f = (ushort_t*)(ws + kOffH0);     // [2][32][1024] fp16 (ping-pong)
  ushort_t* h1f = h0f + 2 * kB * kH;            // [2][32][1024] fp16
  float* gates0 = (float*)(h1f + 2 * kB * kH);
  float* gates1 = gates0 + kB * kNG;

  __shared__ __align__(16) char sb[kLdsBytes];
  uint4* wb4   = (uint4*)sb;                    // weight B-fragments
  float* redp  = (float*)(sb + kRedOff);        // K-stripe reduce
  float* ih_sh = (float*)(sb + kIhOff);
  float* fh_sh = (float*)(sb + kFhOff);

  // signal: drain own write-through stores, rendezvous, tid0 publishes flag
  auto signal = [&](unsigned* arr, unsigned v) {
    asm volatile("s_waitcnt vmcnt(0)" ::: "memory");
    __syncthreads();
    if (tid == 0) st_flag(&arr[bid * 16], v);
  };
  // >= wait (monotone flags, can't-miss); poison/stale-neg handled: (int) diff
  auto wait_ge = [&](unsigned* arr, int lo, int n, int tgt) {
    if (tid < n) {
      while ((int)(ld_flag(&arr[(lo + tid) * 16]) - (unsigned)tgt) < 0)
        __builtin_amdgcn_s_sleep(2);
    }
    __syncthreads();
    asm volatile("" ::: "memory");
  };
  // central equality barrier (r8-r15-proven two-hop shape) for init only
  unsigned iseq = 0;
  auto initbar = [&]() {
    ++iseq;
    asm volatile("s_waitcnt vmcnt(0)" ::: "memory");
    __syncthreads();
    if (bid == 0) {
      if (tid >= 1 && tid < kNBLK) {
        while (ld_flag(&cflags[tid * 16]) != iseq) __builtin_amdgcn_s_sleep(2);
      }
      __syncthreads();
      if (tid == 0) st_flag(cgenp, iseq);
    } else {
      if (tid == 0) {
        st_flag(&cflags[bid * 16], iseq);
        while (ld_flag(cgenp) != iseq) __builtin_amdgcn_s_sleep(2);
      }
      __syncthreads();
    }
    asm volatile("" ::: "memory");
  };

  // ---- A-phase block type ----
  int L, ntile, cb0;
  if (bid < 32)       { L = 0; ntile = 3; cb0 = bid * 48; }
  else if (bid < 120) { L = 0; ntile = 2; cb0 = 1536 + (bid - 32) * 32; }
  else                { L = 1; ntile = 2; cb0 = (bid - 120) * 32; }
  const int K   = L ? 2048 : 1536;
  const int ts4 = K * 2;
  const bool three = (ntile == 3);
  const int rstride = three ? 3 : 2;
  const ushort_t* wf = L ? wf1u : wf0u;
  const float* blp = L ? bl1 : bl0;
  const float* bvp = L ? bv1 : bv0;
  float* gatesL = L ? gates1 : gates0;

  const int lane = tid & 63;
  const int rt   = (tid >> 6) & 1;
  const int str  = tid >> 7;
  const int r_   = rt * 16 + (lane & 15);
  const int koct = lane >> 4;
  const int colg0 = cb0 + (lane & 15);
  const int colg1 = cb0 + 16 + (lane & 15);
  const int colg2 = cb0 + 32 + (lane & 15);

  auto redsl = [&](int slot, int accIdx) -> float* {
    return &redp[(((slot * 2 + rt) * rstride) + accIdx) * 256 + lane * 4];
  };

  // ---- one-time: build weight B-fragments in LDS (lane-linear; r12+-proven) ----
  for (int tt = 0; tt < ntile; ++tt) {
    const int colb = cb0 + tt * 16;
    for (int idx = tid; idx < ts4; idx += kNTHR) {
      int m = idx >> 6, l2 = idx & 63;
      size_t off = (size_t)(colb + (l2 & 15)) * K + m * 32 + 8 * (l2 >> 4);
      wb4[tt * ts4 + idx] = *(const uint4*)(wf + off);
    }
  }
  const float b0w = (colg0 < 4096) ? blp[colg0] : bvp[colg0 - 4096];
  const float b1w = (colg1 < 4096) ? blp[colg1] : bvp[colg1 - 4096];
  const float b2w = three ? ((colg2 < 4096) ? blp[colg2] : bvp[colg2 - 4096]) : 0.f;
  __syncthreads();

  // ---- init: reset flags, zero all 4 h buffers, two central barriers ----
  if (tid == 0) { st_flag(&flagA[bid * 16], 0u); st_flag(&flagB[bid * 16], 0u); }
  { int idx = bid * kNTHR + tid;
    if (idx < 65536) st_wtu((unsigned*)h0f + idx, 0u); }  // 256 KB = 65536 dwords
  float creg = 0.f;
  initbar();   // target 1
  initbar();   // target 2 (stale-proof pair; prev-replay values never match 1)

  // phase-B cell update: single-wave softmax (wave 0), 1 syncthreads
  const int pbB  = (bid & 127) >> 2;
  const int qq4B = bid & 3;
  auto cellB = [&](const float* gbase, ushort_t* hb, float& cr, float* outp, int t) {
    const float* gr = gbase + (size_t)pbB * kNG;
    const bool cl = tid < 256;
    float vi = 0.f, vf = 0.f, vo = 0.f, vg = 0.f;
    int j = qq4B * 256 + tid;
    if (cl) {
      vi = ld_coh(gr + j);
      vf = ld_coh(gr + kH + j);
      vo = ld_coh(gr + 2 * kH + j);
      vg = ld_coh(gr + 3 * kH + j);
    }
    if (tid < 64) {
      float a0i = ld_coh(gr + 4096 + 2 * tid);
      float a1i = ld_coh(gr + 4096 + 2 * tid + 1);
      float a0f = ld_coh(gr + 4096 + kLV + 2 * tid);
      float a1f = ld_coh(gr + 4096 + kLV + 2 * tid + 1);
      float mi = fmaxf(a0i, a1i), mf = fmaxf(a0f, a1f);
#pragma unroll
      for (int d = 32; d > 0; d >>= 1) {
        mi = fmaxf(mi, __shfl_xor(mi, d));
        mf = fmaxf(mf, __shfl_xor(mf, d));
      }
      float e0i = __expf(a0i - mi), e1i = __expf(a1i - mi);
      float e0f = __expf(a0f - mf), e1f = __expf(a1f - mf);
      float si2 = e0i + e1i, sf2 = e0f + e1f;
      float Pi = si2, Pf = sf2;
#pragma unroll
      for (int d = 1; d < 64; d <<= 1) {
        float ni = __shfl_up(Pi, d);
        float nf = __shfl_up(Pf, d);
        if (tid >= d) { Pi += ni; Pf += nf; }
      }
      float Si = __shfl(Pi, 63), Sf = __shfl(Pf, 63);
      float pri = Pi - si2, prf = Pf - sf2;    // exclusive prefixes
      ih_sh[2 * tid]     = (prf + e0f) / Sf;           // cumsum(softmax(f_h))
      ih_sh[2 * tid + 1] = (prf + e0f + e1f) / Sf;
      fh_sh[2 * tid]     = (Si - pri) / Si;            // == (Si - incl + e)/Si
      fh_sh[2 * tid + 1] = (Si - pri - e0i) / Si;
    }
    __syncthreads();
    if (cl) {
      float i_ = 1.f / (1.f + __expf(-vi));
      float f_ = 1.f / (1.f + __expf(-vf));
      float o_ = 1.f / (1.f + __expf(-vo));
      float g_ = tanhf(vg);
      int l2 = j >> 3;
      float ih = ih_sh[l2], fh = fh_sh[l2];
      float w  = ih * fh;
      float cold = cr;
      float cn = w * (f_ * cold + i_ * g_) + (fh - w) * cold + (ih - w) * g_;
      float hn = o_ * tanhf(cn);
      cr = cn;
      float hnn = __shfl_xor(hn, 1);
      if (!(tid & 1))
        st_wtu((unsigned*)hb + ((size_t)pbB * kH + j) / 2, pkrtz(hn, hnn));
      if (outp) st_wt(outp + ((size_t)pbB * kT + t) * kH + j, hn);
    }
  };

  for (int e = 0; e <= kT; ++e) {
    const bool actA = L ? (e >= 1) : (e < kT);
    const size_t wpar = (size_t)(e & 1) * kB * kH;        // B writes parity e&1
    const size_t rpar = (size_t)((e + 1) & 1) * kB * kH;  // A reads parity (e-1)&1

    // ========== Phase A ==========
    if (actA) {
      floatx4 a0 = {0.f,0.f,0.f,0.f}, a1 = a0, a2 = a0;
      if (L == 0) {
        // x segment BEFORE the wait (x is input-only; overlaps B stragglers)
        const float* bx = x + ((size_t)r_ * kT + e) * kD + str * 32 + koct * 8;
        vfloat4 vx[8];
#pragma unroll
        for (int j = 0; j < 4; ++j) {
          vx[2*j]   = *(const vfloat4*)(bx + j * 128);
          vx[2*j+1] = *(const vfloat4*)(bx + j * 128 + 4);
        }
        uint4 pa[4];
#pragma unroll
        for (int j = 0; j < 4; ++j) pa[j] = pack2(vx[2*j], vx[2*j+1]);
#pragma unroll
        for (int j = 0; j < 4; ++j) {
          const int m = str + 4 * j;
          a0 = mfma16(pa[j], wb4[m * 64 + lane], a0);
          a1 = mfma16(pa[j], wb4[ts4 + m * 64 + lane], a1);
          if (three) a2 = mfma16(pa[j], wb4[2 * ts4 + m * 64 + lane], a2);
        }
      }
      // A-wait: h producers of epoch e-1 (skip at e=0: h = zeroed buffers)
      if (e > 0) {
        if (bid < 120) wait_ge(flagB, 0, 128, e + 1);   // L0-A: h0 writers
        else           wait_ge(flagB, 0, 256, e + 1);   // L1-A: h0+h1 writers
      }
      if (L == 0) {
        uint4 pa[8];
        ld8h(pa, h0f + rpar + (size_t)r_ * kH + str * 32 + koct * 8);
#pragma unroll
        for (int j = 0; j < 8; ++j) {
          const int m = 16 + str + 4 * j;
          a0 = mfma16(pa[j], wb4[m * 64 + lane], a0);
          a1 = mfma16(pa[j], wb4[ts4 + m * 64 + lane], a1);
          if (three) a2 = mfma16(pa[j], wb4[2 * ts4 + m * 64 + lane], a2);
        }
      } else {
        uint4 pa[8], pb[8];
        ld8h2(pa, pb, h0f + rpar + (size_t)r_ * kH + str * 32 + koct * 8,
                      h1f + rpar + (size_t)r_ * kH + str * 32 + koct * 8);
#pragma unroll
        for (int j = 0; j < 8; ++j) {
          const int m = str + 4 * j;
          a0 = mfma16(pa[j], wb4[m * 64 + lane], a0);
          a1 = mfma16(pa[j], wb4[ts4 + m * 64 + lane], a1);
        }
#pragma unroll
        for (int j = 0; j < 8; ++j) {
          const int m = 32 + str + 4 * j;
          a0 = mfma16(pb[j], wb4[m * 64 + lane], a0);
          a1 = mfma16(pb[j], wb4[ts4 + m * 64 + lane], a1);
        }
      }
      // K-stripe reduce (r16-proven)
      if (!three) {
        if (str != 0) {
          *(floatx4*)redsl(str - 1, 0) = a0;
          *(floatx4*)redsl(str - 1, 1) = a1;
        }
        __syncthreads();
        if (str == 0) {
#pragma unroll
          for (int s2 = 0; s2 < 3; ++s2) {
            a0 += *(const floatx4*)redsl(s2, 0);
            a1 += *(const floatx4*)redsl(s2, 1);
          }
        }
      } else {
        if (str == 1 || str == 2) {
          *(floatx4*)redsl(str - 1, 0) = a0;
          *(floatx4*)redsl(str - 1, 1) = a1;
          *(floatx4*)redsl(str - 1, 2) = a2;
        }
        __syncthreads();
        if (str == 0) {
#pragma unroll
          for (int s2 = 0; s2 < 2; ++s2) {
            a0 += *(const floatx4*)redsl(s2, 0);
            a1 += *(const floatx4*)redsl(s2, 1);
            a2 += *(const floatx4*)redsl(s2, 2);
          }
        }
        __syncthreads();
        if (str == 3) {
          *(floatx4*)redsl(0, 0) = a0;
          *(floatx4*)redsl(0, 1) = a1;
          *(floatx4*)redsl(0, 2) = a2;
        }
        __syncthreads();
        if (str == 0) {
          a0 += *(const floatx4*)redsl(0, 0);
          a1 += *(const floatx4*)redsl(0, 1);
          a2 += *(const floatx4*)redsl(0, 2);
        }
      }
      if (str == 0) {
        const int rb = rt * 16 + koct * 4;
#pragma unroll
        for (int r = 0; r < 4; ++r)
          st_wt(gatesL + (size_t)(rb + r) * kNG + colg0, a0[r] + b0w);
#pragma unroll
        for (int r = 0; r < 4; ++r)
          st_wt(gatesL + (size_t)(rb + r) * kNG + colg1, a1[r] + b1w);
        if (three) {
#pragma unroll
          for (int r = 0; r < 4; ++r)
            st_wt(gatesL + (size_t)(rb + r) * kNG + colg2, a2[r] + b2w);
        }
      }
    }
    signal(flagA, (unsigned)(e + 1));

    // ========== Phase B ==========
    if (bid < 128) {
      if (e < kT) {
        // gates0 ready: flagA[0..119] >= e+1; WAR on h0f[e&1] (epoch e-1
        // readers incl. L1-A): flagA[120..255] >= e  -> 1-epoch slack vs L1
        if (tid < 256) {
          int tgt = (tid < 120) ? e + 1 : e;
          while ((int)(ld_flag(&flagA[tid * 16]) - (unsigned)tgt) < 0)
            __builtin_amdgcn_s_sleep(2);
        }
        __syncthreads();
        asm volatile("" ::: "memory");
        cellB(gates0, h0f + wpar, creg, nullptr, e);
      }
    } else {
      if (e >= 1) {
        wait_ge(flagA, 120, 136, e + 1);   // gates1 + h1f WAR (own cohort)
        cellB(gates1, h1f + wpar, creg, out, e - 1);
      }
    }
    signal(flagB, (unsigned)(e + 2));
  }
}

extern "C" void kernel_launch(void* const* d_in, const int* in_sizes, int n_in,
                              void* d_out, int out_size, void* d_ws, size_t ws_size,
                              hipStream_t stream) {
  const float* x   = (const float*)d_in[0];
  const float* Wl0 = (const float*)d_in[1];
  const float* bl0 = (const float*)d_in[2];
  const float* Wv0 = (const float*)d_in[3];
  const float* bv0 = (const float*)d_in[4];
  const float* Wl1 = (const float*)d_in[5];
  const float* bl1 = (const float*)d_in[6];
  const float* Wv1 = (const float*)d_in[7];
  const float* bv1 = (const float*)d_in[8];
  (void)in_sizes; (void)n_in; (void)out_size; (void)ws_size;

  float* ws = (float*)d_ws;
  // h region: 2 x [2][32][1024] fp16 = 256 KB = 65536 floats; gates after
  float* gatesEnd = ws + kOffH0 + 65536 / 2 * 2;  // kOffH0 + 65536 floats? see kernel
  (void)gatesEnd;
  const size_t kOffWFf = (size_t)kOffH0 + 32768 + 32768 + 2 * (size_t)kB * kNG;
  ushort_t* wf0 = (ushort_t*)(ws + kOffWFf);               // [4352][1536] fp16
  ushort_t* wf1 = wf0 + (size_t)4352 * 1536;               // [4352][2048] fp16

  {
    int n;
    n = 4096 * 1536 / 8;
    cvt_fp16_kernel<<<(n + 255) / 256, 256, 0, stream>>>(Wl0, wf0, n);
    n = 256 * 1536 / 8;
    cvt_fp16_kernel<<<(n + 255) / 256, 256, 0, stream>>>(
        Wv0, wf0 + (size_t)4096 * 1536, n);
    n = 4096 * 2048 / 8;
    cvt_fp16_kernel<<<(n + 255) / 256, 256, 0, stream>>>(Wl1, wf1, n);
    n = 256 * 2048 / 8;
    cvt_fp16_kernel<<<(n + 255) / 256, 256, 0, stream>>>(
        Wv1, wf1 + (size_t)4096 * 2048, n);
  }

  onlstm_kernel<<<dim3(kNBLK), dim3(kNTHR), 0, stream>>>(
      x, bl0, bv0, bl1, bv1, wf0, wf1, (float*)d_out, ws);
}

// Round 18
// 9863.714 us; speedup vs baseline: 4.5871x; 1.0049x over previous
//
#include <hip/hip_runtime.h>

namespace {
constexpr int kB  = 32;
constexpr int kT  = 1024;
constexpr int kD  = 512;
constexpr int kH  = 1024;
constexpr int kLV = 128;
constexpr int kNG = 4 * kH + 2 * kLV;   // 4352
constexpr int kNBLK = 256;
constexpr int kNTHR = 512;
// ws uint offsets: flagA[0..4095], flagB[4096..8191], cflags[8192..12287], cgenp[12288]
constexpr int kOffH0 = 16384;           // float offset of h region
// LDS byte offsets
constexpr int kRedOff = 3 * 1536 * 2 * 16;   // weight region max: 147456 B
constexpr int kIhOff  = kRedOff + 12288;
constexpr int kFhOff  = kIhOff + 512;
constexpr int kLdsBytes = kFhOff + 512;      // 160,768 <= 163,840
}

typedef float vfloat4 __attribute__((ext_vector_type(4)));
typedef float floatx4 __attribute__((ext_vector_type(4)));
typedef _Float16 half8_t __attribute__((ext_vector_type(8)));
typedef unsigned short ushort_t;

static __device__ __forceinline__ unsigned ld_flag(const unsigned* p) {
  return __hip_atomic_load(p, __ATOMIC_RELAXED, __HIP_MEMORY_SCOPE_AGENT);
}
static __device__ __forceinline__ void st_flag(unsigned* p, unsigned v) {
  __hip_atomic_store(p, v, __ATOMIC_RELAXED, __HIP_MEMORY_SCOPE_AGENT);
}
static __device__ __forceinline__ float ld_coh(const float* p) {
  return __hip_atomic_load(p, __ATOMIC_RELAXED, __HIP_MEMORY_SCOPE_AGENT);
}
static __device__ __forceinline__ void st_wt(float* p, float v) {
  asm volatile("global_store_dword %0, %1, off sc0 sc1" :: "v"(p), "v"(v) : "memory");
}
static __device__ __forceinline__ void st_wtu(unsigned* p, unsigned v) {
  asm volatile("global_store_dword %0, %1, off sc0 sc1" :: "v"(p), "v"(v) : "memory");
}
// 8 coherent 16B fp16 loads, completed INSIDE one asm block (proven r5-r17).
static __device__ __forceinline__ void ld8h(uint4 v[8], const ushort_t* b) {
  asm volatile(
      "global_load_dwordx4 %0, %8, off sc0 sc1\n\t"
      "global_load_dwordx4 %1, %8, off offset:256 sc0 sc1\n\t"
      "global_load_dwordx4 %2, %8, off offset:512 sc0 sc1\n\t"
      "global_load_dwordx4 %3, %8, off offset:768 sc0 sc1\n\t"
      "global_load_dwordx4 %4, %8, off offset:1024 sc0 sc1\n\t"
      "global_load_dwordx4 %5, %8, off offset:1280 sc0 sc1\n\t"
      "global_load_dwordx4 %6, %8, off offset:1536 sc0 sc1\n\t"
      "global_load_dwordx4 %7, %8, off offset:1792 sc0 sc1\n\t"
      "s_waitcnt vmcnt(0)"
      : "=&v"(v[0]), "=&v"(v[1]), "=&v"(v[2]), "=&v"(v[3]),
        "=&v"(v[4]), "=&v"(v[5]), "=&v"(v[6]), "=&v"(v[7])
      : "v"(b)
      : "memory");
}
static __device__ __forceinline__ unsigned pkrtz(float a, float b) {
  return __builtin_bit_cast(unsigned, __builtin_amdgcn_cvt_pkrtz(a, b));
}
static __device__ __forceinline__ uint4 pack2(vfloat4 a, vfloat4 b) {
  uint4 r;
  r.x = pkrtz(a.x, a.y); r.y = pkrtz(a.z, a.w);
  r.z = pkrtz(b.x, b.y); r.w = pkrtz(b.z, b.w);
  return r;
}
static __device__ __forceinline__ floatx4 mfma16(uint4 a, uint4 b, floatx4 c) {
  return __builtin_amdgcn_mfma_f32_16x16x32_f16(
      __builtin_bit_cast(half8_t, a), __builtin_bit_cast(half8_t, b), c, 0, 0, 0);
}

// -------- fp32 -> fp16 weight conversion (one-time pre-pass) --------
__global__ __launch_bounds__(256) void cvt_fp16_kernel(
    const float* __restrict__ src, ushort_t* __restrict__ dst, int n8) {
  int i = blockIdx.x * 256 + threadIdx.x;
  if (i >= n8) return;
  const vfloat4* s4 = (const vfloat4*)src;
  vfloat4 a = s4[2 * i], b = s4[2 * i + 1];
  typedef _Float16 h8 __attribute__((ext_vector_type(8)));
  h8 o;
  o[0] = (_Float16)a.x; o[1] = (_Float16)a.y;
  o[2] = (_Float16)a.z; o[3] = (_Float16)a.w;
  o[4] = (_Float16)b.x; o[5] = (_Float16)b.y;
  o[6] = (_Float16)b.z; o[7] = (_Float16)b.w;
  ((h8*)dst)[i] = o;
}

__global__ __launch_bounds__(kNTHR, 2) void onlstm_kernel(
    const float* __restrict__ x,
    const float* __restrict__ bl0, const float* __restrict__ bv0,
    const float* __restrict__ bl1, const float* __restrict__ bv1,
    const ushort_t* __restrict__ wf0u, const ushort_t* __restrict__ wf1u,
    float* __restrict__ out, float* __restrict__ ws)
{
  const int tid = threadIdx.x;
  const int bid = blockIdx.x;

  // ---- workspace ----
  unsigned* flagA  = (unsigned*)ws;             // [256] stride-16
  unsigned* flagB  = (unsigned*)ws + 4096;      // [256] stride-16
  unsigned* cflags = (unsigned*)ws + 8192;      // init-barrier flags
  unsigned* cgenp  = (unsigned*)ws + 12288;     // init-barrier generation
  ushort_t* h0f = (ushort_t*)(ws + kOffH0);     // [2][32][1024] fp16 (ping-pong)
  ushort_t* h1f = h0f + 2 * kB * kH;            // [2][32][1024] fp16
  float* gates0 = (float*)(h1f + 2 * kB * kH);
  float* gates1 = gates0 + kB * kNG;

  __shared__ __align__(16) char sb[kLdsBytes];
  uint4* wb4   = (uint4*)sb;                    // weight B-fragments
  float* redp  = (float*)(sb + kRedOff);        // K-stripe reduce
  float* ih_sh = (float*)(sb + kIhOff);
  float* fh_sh = (float*)(sb + kFhOff);

  auto signal = [&](unsigned* arr, unsigned v) {
    asm volatile("s_waitcnt vmcnt(0)" ::: "memory");
    __syncthreads();
    if (tid == 0) st_flag(&arr[bid * 16], v);
  };
  auto wait_ge = [&](unsigned* arr, int lo, int n, int tgt) {
    if (tid < n) {
      while ((int)(ld_flag(&arr[(lo + tid) * 16]) - (unsigned)tgt) < 0)
        __builtin_amdgcn_s_sleep(1);
    }
    __syncthreads();
    asm volatile("" ::: "memory");
  };
  unsigned iseq = 0;
  auto initbar = [&]() {                        // r8-r15-proven two-hop shape
    ++iseq;
    asm volatile("s_waitcnt vmcnt(0)" ::: "memory");
    __syncthreads();
    if (bid == 0) {
      if (tid >= 1 && tid < kNBLK) {
        while (ld_flag(&cflags[tid * 16]) != iseq) __builtin_amdgcn_s_sleep(2);
      }
      __syncthreads();
      if (tid == 0) st_flag(cgenp, iseq);
    } else {
      if (tid == 0) {
        st_flag(&cflags[bid * 16], iseq);
        while (ld_flag(cgenp) != iseq) __builtin_amdgcn_s_sleep(2);
      }
      __syncthreads();
    }
    asm volatile("" ::: "memory");
  };

  // ---- A-phase block type ----
  int L, ntile, cb0;
  if (bid < 32)       { L = 0; ntile = 3; cb0 = bid * 48; }
  else if (bid < 120) { L = 0; ntile = 2; cb0 = 1536 + (bid - 32) * 32; }
  else                { L = 1; ntile = 2; cb0 = (bid - 120) * 32; }
  const int K   = L ? 2048 : 1536;
  const int ts4 = K * 2;
  const bool three = (ntile == 3);
  const int rstride = three ? 3 : 2;
  const ushort_t* wf = L ? wf1u : wf0u;
  const float* blp = L ? bl1 : bl0;
  const float* bvp = L ? bv1 : bv0;
  float* gatesL = L ? gates1 : gates0;

  const int lane = tid & 63;
  const int rt   = (tid >> 6) & 1;
  const int str  = tid >> 7;
  const int r_   = rt * 16 + (lane & 15);
  const int koct = lane >> 4;
  const int colg0 = cb0 + (lane & 15);
  const int colg1 = cb0 + 16 + (lane & 15);
  const int colg2 = cb0 + 32 + (lane & 15);

  auto redsl = [&](int slot, int accIdx) -> float* {
    return &redp[(((slot * 2 + rt) * rstride) + accIdx) * 256 + lane * 4];
  };

  // ---- one-time: build weight B-fragments in LDS (lane-linear; r12+-proven) ----
  for (int tt = 0; tt < ntile; ++tt) {
    const int colb = cb0 + tt * 16;
    for (int idx = tid; idx < ts4; idx += kNTHR) {
      int m = idx >> 6, l2 = idx & 63;
      size_t off = (size_t)(colb + (l2 & 15)) * K + m * 32 + 8 * (l2 >> 4);
      wb4[tt * ts4 + idx] = *(const uint4*)(wf + off);
    }
  }
  const float b0w = (colg0 < 4096) ? blp[colg0] : bvp[colg0 - 4096];
  const float b1w = (colg1 < 4096) ? blp[colg1] : bvp[colg1 - 4096];
  const float b2w = three ? ((colg2 < 4096) ? blp[colg2] : bvp[colg2 - 4096]) : 0.f;
  __syncthreads();

  // ---- init: reset flags, zero all 4 h buffers, two central barriers ----
  if (tid == 0) { st_flag(&flagA[bid * 16], 0u); st_flag(&flagB[bid * 16], 0u); }
  { int idx = bid * kNTHR + tid;
    if (idx < 65536) st_wtu((unsigned*)h0f + idx, 0u); }  // 256 KB = 65536 dwords
  float creg = 0.f;
  initbar();   // target 1
  initbar();   // target 2 (stale-proof pair)

  // phase-B cell update: single-wave softmax (r17-proven), 1 syncthreads
  const int pbB  = (bid & 127) >> 2;
  const int qq4B = bid & 3;
  auto cellB = [&](const float* gbase, ushort_t* hb, float& cr, float* outp, int t) {
    const float* gr = gbase + (size_t)pbB * kNG;
    const bool cl = tid < 256;
    float vi = 0.f, vf = 0.f, vo = 0.f, vg = 0.f;
    int j = qq4B * 256 + tid;
    if (cl) {
      vi = ld_coh(gr + j);
      vf = ld_coh(gr + kH + j);
      vo = ld_coh(gr + 2 * kH + j);
      vg = ld_coh(gr + 3 * kH + j);
    }
    if (tid < 64) {
      float a0i = ld_coh(gr + 4096 + 2 * tid);
      float a1i = ld_coh(gr + 4096 + 2 * tid + 1);
      float a0f = ld_coh(gr + 4096 + kLV + 2 * tid);
      float a1f = ld_coh(gr + 4096 + kLV + 2 * tid + 1);
      float mi = fmaxf(a0i, a1i), mf = fmaxf(a0f, a1f);
#pragma unroll
      for (int d = 32; d > 0; d >>= 1) {
        mi = fmaxf(mi, __shfl_xor(mi, d));
        mf = fmaxf(mf, __shfl_xor(mf, d));
      }
      float e0i = __expf(a0i - mi), e1i = __expf(a1i - mi);
      float e0f = __expf(a0f - mf), e1f = __expf(a1f - mf);
      float si2 = e0i + e1i, sf2 = e0f + e1f;
      float Pi = si2, Pf = sf2;
#pragma unroll
      for (int d = 1; d < 64; d <<= 1) {
        float ni = __shfl_up(Pi, d);
        float nf = __shfl_up(Pf, d);
        if (tid >= d) { Pi += ni; Pf += nf; }
      }
      float Si = __shfl(Pi, 63), Sf = __shfl(Pf, 63);
      float pri = Pi - si2, prf = Pf - sf2;    // exclusive prefixes
      ih_sh[2 * tid]     = (prf + e0f) / Sf;
      ih_sh[2 * tid + 1] = (prf + e0f + e1f) / Sf;
      fh_sh[2 * tid]     = (Si - pri) / Si;
      fh_sh[2 * tid + 1] = (Si - pri - e0i) / Si;
    }
    __syncthreads();
    if (cl) {
      float i_ = 1.f / (1.f + __expf(-vi));
      float f_ = 1.f / (1.f + __expf(-vf));
      float o_ = 1.f / (1.f + __expf(-vo));
      float g_ = tanhf(vg);
      int l2 = j >> 3;
      float ih = ih_sh[l2], fh = fh_sh[l2];
      float w  = ih * fh;
      float cold = cr;
      float cn = w * (f_ * cold + i_ * g_) + (fh - w) * cold + (ih - w) * g_;
      float hn = o_ * tanhf(cn);
      cr = cn;
      float hnn = __shfl_xor(hn, 1);
      if (!(tid & 1))
        st_wtu((unsigned*)hb + ((size_t)pbB * kH + j) / 2, pkrtz(hn, hnn));
      if (outp) st_wt(outp + ((size_t)pbB * kT + t) * kH + j, hn);
    }
  };

  for (int e = 0; e <= kT; ++e) {
    const bool actA = L ? (e >= 1) : (e < kT);
    const size_t wpar = (size_t)(e & 1) * kB * kH;        // B writes parity e&1
    const size_t rpar = (size_t)((e + 1) & 1) * kB * kH;  // A reads parity (e-1)&1

    // ========== Phase A ==========
    if (actA) {
      floatx4 a0 = {0.f,0.f,0.f,0.f}, a1 = a0, a2 = a0;
      if (L == 0) {
        // x segment BEFORE the wait (input-only; overlaps B stragglers)
        const float* bx = x + ((size_t)r_ * kT + e) * kD + str * 32 + koct * 8;
        vfloat4 vx[8];
#pragma unroll
        for (int j = 0; j < 4; ++j) {
          vx[2*j]   = *(const vfloat4*)(bx + j * 128);
          vx[2*j+1] = *(const vfloat4*)(bx + j * 128 + 4);
        }
        uint4 pa[4];
#pragma unroll
        for (int j = 0; j < 4; ++j) pa[j] = pack2(vx[2*j], vx[2*j+1]);
#pragma unroll
        for (int j = 0; j < 4; ++j) {
          const int m = str + 4 * j;
          a0 = mfma16(pa[j], wb4[m * 64 + lane], a0);
          a1 = mfma16(pa[j], wb4[ts4 + m * 64 + lane], a1);
          if (three) a2 = mfma16(pa[j], wb4[2 * ts4 + m * 64 + lane], a2);
        }
        // h0 wait: own-chain edge (L0-B(e-1))
        if (e > 0) wait_ge(flagB, 0, 128, e + 1);
        uint4 ph[8];
        ld8h(ph, h0f + rpar + (size_t)r_ * kH + str * 32 + koct * 8);
#pragma unroll
        for (int j = 0; j < 8; ++j) {
          const int m = 16 + str + 4 * j;
          a0 = mfma16(ph[j], wb4[m * 64 + lane], a0);
          a1 = mfma16(ph[j], wb4[ts4 + m * 64 + lane], a1);
          if (three) a2 = mfma16(ph[j], wb4[2 * ts4 + m * 64 + lane], a2);
        }
      } else {
        // SPLIT WAIT (r18): h0 edge is slack (L0 chain leads) -> load h0 and
        // run its MFMAs while L1-B stragglers finish h1. Only h1 is tight.
        wait_ge(flagB, 0, 128, e + 1);          // h0 ready (early edge)
        uint4 pa[8];
        ld8h(pa, h0f + rpar + (size_t)r_ * kH + str * 32 + koct * 8);
#pragma unroll
        for (int j = 0; j < 8; ++j) {
          const int m = str + 4 * j;
          a0 = mfma16(pa[j], wb4[m * 64 + lane], a0);
          a1 = mfma16(pa[j], wb4[ts4 + m * 64 + lane], a1);
        }
        wait_ge(flagB, 128, 128, e + 1);        // h1 ready (tight edge)
        uint4 pb[8];
        ld8h(pb, h1f + rpar + (size_t)r_ * kH + str * 32 + koct * 8);
#pragma unroll
        for (int j = 0; j < 8; ++j) {
          const int m = 32 + str + 4 * j;
          a0 = mfma16(pb[j], wb4[m * 64 + lane], a0);
          a1 = mfma16(pb[j], wb4[ts4 + m * 64 + lane], a1);
        }
      }
      // K-stripe reduce (r16/r17-proven)
      if (!three) {
        if (str != 0) {
          *(floatx4*)redsl(str - 1, 0) = a0;
          *(floatx4*)redsl(str - 1, 1) = a1;
        }
        __syncthreads();
        if (str == 0) {
#pragma unroll
          for (int s2 = 0; s2 < 3; ++s2) {
            a0 += *(const floatx4*)redsl(s2, 0);
            a1 += *(const floatx4*)redsl(s2, 1);
          }
        }
      } else {
        if (str == 1 || str == 2) {
          *(floatx4*)redsl(str - 1, 0) = a0;
          *(floatx4*)redsl(str - 1, 1) = a1;
          *(floatx4*)redsl(str - 1, 2) = a2;
        }
        __syncthreads();
        if (str == 0) {
#pragma unroll
          for (int s2 = 0; s2 < 2; ++s2) {
            a0 += *(const floatx4*)redsl(s2, 0);
            a1 += *(const floatx4*)redsl(s2, 1);
            a2 += *(const floatx4*)redsl(s2, 2);
          }
        }
        __syncthreads();
        if (str == 3) {
          *(floatx4*)redsl(0, 0) = a0;
          *(floatx4*)redsl(0, 1) = a1;
          *(floatx4*)redsl(0, 2) = a2;
        }
        __syncthreads();
        if (str == 0) {
          a0 += *(const floatx4*)redsl(0, 0);
          a1 += *(const floatx4*)redsl(0, 1);
          a2 += *(const floatx4*)redsl(0, 2);
        }
      }
      if (str == 0) {
        const int rb = rt * 16 + koct * 4;
#pragma unroll
        for (int r = 0; r < 4; ++r)
          st_wt(gatesL + (size_t)(rb + r) * kNG + colg0, a0[r] + b0w);
#pragma unroll
        for (int r = 0; r < 4; ++r)
          st_wt(gatesL + (size_t)(rb + r) * kNG + colg1, a1[r] + b1w);
        if (three) {
#pragma unroll
          for (int r = 0; r < 4; ++r)
            st_wt(gatesL + (size_t)(rb + r) * kNG + colg2, a2[r] + b2w);
        }
      }
    }
    signal(flagA, (unsigned)(e + 1));

    // ========== Phase B ==========
    if (bid < 128) {
      if (e < kT) {
        // gates0 ready: flagA[0..119] >= e+1; h0f WAR vs L1-A(e-1): >= e
        if (tid < 256) {
          int tgt = (tid < 120) ? e + 1 : e;
          while ((int)(ld_flag(&flagA[tid * 16]) - (unsigned)tgt) < 0)
            __builtin_amdgcn_s_sleep(1);
        }
        __syncthreads();
        asm volatile("" ::: "memory");
        cellB(gates0, h0f + wpar, creg, nullptr, e);
      }
    } else {
      if (e >= 1) {
        wait_ge(flagA, 120, 136, e + 1);   // gates1 + h1f WAR (own cohort)
        cellB(gates1, h1f + wpar, creg, out, e - 1);
      }
    }
    signal(flagB, (unsigned)(e + 2));
  }
}

extern "C" void kernel_launch(void* const* d_in, const int* in_sizes, int n_in,
                              void* d_out, int out_size, void* d_ws, size_t ws_size,
                              hipStream_t stream) {
  const float* x   = (const float*)d_in[0];
  const float* Wl0 = (const float*)d_in[1];
  const float* bl0 = (const float*)d_in[2];
  const float* Wv0 = (const float*)d_in[3];
  const float* bv0 = (const float*)d_in[4];
  const float* Wl1 = (const float*)d_in[5];
  const float* bl1 = (const float*)d_in[6];
  const float* Wv1 = (const float*)d_in[7];
  const float* bv1 = (const float*)d_in[8];
  (void)in_sizes; (void)n_in; (void)out_size; (void)ws_size;

  float* ws = (float*)d_ws;
  const size_t kOffWFf = (size_t)kOffH0 + 32768 + 32768 + 2 * (size_t)kB * kNG;
  ushort_t* wf0 = (ushort_t*)(ws + kOffWFf);               // [4352][1536] fp16
  ushort_t* wf1 = wf0 + (size_t)4352 * 1536;               // [4352][2048] fp16

  {
    int n;
    n = 4096 * 1536 / 8;
    cvt_fp16_kernel<<<(n + 255) / 256, 256, 0, stream>>>(Wl0, wf0, n);
    n = 256 * 1536 / 8;
    cvt_fp16_kernel<<<(n + 255) / 256, 256, 0, stream>>>(
        Wv0, wf0 + (size_t)4096 * 1536, n);
    n = 4096 * 2048 / 8;
    cvt_fp16_kernel<<<(n + 255) / 256, 256, 0, stream>>>(Wl1, wf1, n);
    n = 256 * 2048 / 8;
    cvt_fp16_kernel<<<(n + 255) / 256, 256, 0, stream>>>(
        Wv1, wf1 + (size_t)4096 * 2048, n);
  }

  onlstm_kernel<<<dim3(kNBLK), dim3(kNTHR), 0, stream>>>(
      x, bl0, bv0, bl1, bv1, wf0, wf1, (float*)d_out, ws);
}

// Round 19
// 9606.379 us; speedup vs baseline: 4.7100x; 1.0268x over previous
//
#include <hip/hip_runtime.h>

namespace {
constexpr int kB  = 32;
constexpr int kT  = 1024;
constexpr int kD  = 512;
constexpr int kH  = 1024;
constexpr int kLV = 128;
constexpr int kNG = 4 * kH + 2 * kLV;   // 4352
constexpr int kNBLK = 256;
constexpr int kNTHR = 512;
// ws uint offsets: flagA[0..4095], flagB[4096..8191], cflags[8192..12287], cgenp[12288]
constexpr int kOffH0 = 16384;           // float offset of h region
// LDS byte offsets
constexpr int kRedOff = 3 * 1536 * 2 * 16;   // weight region max: 147456 B
constexpr int kIhOff  = kRedOff + 12288;
constexpr int kFhOff  = kIhOff + 512;
constexpr int kLdsBytes = kFhOff + 512;      // 160,768 <= 163,840
}

typedef float vfloat4 __attribute__((ext_vector_type(4)));
typedef float floatx4 __attribute__((ext_vector_type(4)));
typedef _Float16 half8_t __attribute__((ext_vector_type(8)));
typedef unsigned short ushort_t;

static __device__ __forceinline__ unsigned ld_flag(const unsigned* p) {
  return __hip_atomic_load(p, __ATOMIC_RELAXED, __HIP_MEMORY_SCOPE_AGENT);
}
static __device__ __forceinline__ void st_flag(unsigned* p, unsigned v) {
  __hip_atomic_store(p, v, __ATOMIC_RELAXED, __HIP_MEMORY_SCOPE_AGENT);
}
static __device__ __forceinline__ float ld_coh(const float* p) {
  return __hip_atomic_load(p, __ATOMIC_RELAXED, __HIP_MEMORY_SCOPE_AGENT);
}
static __device__ __forceinline__ void st_wt(float* p, float v) {
  asm volatile("global_store_dword %0, %1, off sc0 sc1" :: "v"(p), "v"(v) : "memory");
}
static __device__ __forceinline__ void st_wtu(unsigned* p, unsigned v) {
  asm volatile("global_store_dword %0, %1, off sc0 sc1" :: "v"(p), "v"(v) : "memory");
}
// 8 coherent 16B fp16 loads, completed INSIDE one asm block (proven r5-r18).
static __device__ __forceinline__ void ld8h(uint4 v[8], const ushort_t* b) {
  asm volatile(
      "global_load_dwordx4 %0, %8, off sc0 sc1\n\t"
      "global_load_dwordx4 %1, %8, off offset:256 sc0 sc1\n\t"
      "global_load_dwordx4 %2, %8, off offset:512 sc0 sc1\n\t"
      "global_load_dwordx4 %3, %8, off offset:768 sc0 sc1\n\t"
      "global_load_dwordx4 %4, %8, off offset:1024 sc0 sc1\n\t"
      "global_load_dwordx4 %5, %8, off offset:1280 sc0 sc1\n\t"
      "global_load_dwordx4 %6, %8, off offset:1536 sc0 sc1\n\t"
      "global_load_dwordx4 %7, %8, off offset:1792 sc0 sc1\n\t"
      "s_waitcnt vmcnt(0)"
      : "=&v"(v[0]), "=&v"(v[1]), "=&v"(v[2]), "=&v"(v[3]),
        "=&v"(v[4]), "=&v"(v[5]), "=&v"(v[6]), "=&v"(v[7])
      : "v"(b)
      : "memory");
}
static __device__ __forceinline__ unsigned pkrtz(float a, float b) {
  return __builtin_bit_cast(unsigned, __builtin_amdgcn_cvt_pkrtz(a, b));
}
static __device__ __forceinline__ uint4 pack2(vfloat4 a, vfloat4 b) {
  uint4 r;
  r.x = pkrtz(a.x, a.y); r.y = pkrtz(a.z, a.w);
  r.z = pkrtz(b.x, b.y); r.w = pkrtz(b.z, b.w);
  return r;
}
static __device__ __forceinline__ floatx4 mfma16(uint4 a, uint4 b, floatx4 c) {
  return __builtin_amdgcn_mfma_f32_16x16x32_f16(
      __builtin_bit_cast(half8_t, a), __builtin_bit_cast(half8_t, b), c, 0, 0, 0);
}

// -------- fp32 -> fp16 weight conversion (one-time pre-pass) --------
__global__ __launch_bounds__(256) void cvt_fp16_kernel(
    const float* __restrict__ src, ushort_t* __restrict__ dst, int n8) {
  int i = blockIdx.x * 256 + threadIdx.x;
  if (i >= n8) return;
  const vfloat4* s4 = (const vfloat4*)src;
  vfloat4 a = s4[2 * i], b = s4[2 * i + 1];
  typedef _Float16 h8 __attribute__((ext_vector_type(8)));
  h8 o;
  o[0] = (_Float16)a.x; o[1] = (_Float16)a.y;
  o[2] = (_Float16)a.z; o[3] = (_Float16)a.w;
  o[4] = (_Float16)b.x; o[5] = (_Float16)b.y;
  o[6] = (_Float16)b.z; o[7] = (_Float16)b.w;
  ((h8*)dst)[i] = o;
}

__global__ __launch_bounds__(kNTHR, 2) void onlstm_kernel(
    const float* __restrict__ x,
    const float* __restrict__ bl0, const float* __restrict__ bv0,
    const float* __restrict__ bl1, const float* __restrict__ bv1,
    const ushort_t* __restrict__ wf0u, const ushort_t* __restrict__ wf1u,
    float* __restrict__ out, float* __restrict__ ws)
{
  const int tid = threadIdx.x;
  const int bid = blockIdx.x;

  // ---- workspace ----
  unsigned* flagA  = (unsigned*)ws;             // [256] stride-16
  unsigned* flagB  = (unsigned*)ws + 4096;      // [256] stride-16
  unsigned* cflags = (unsigned*)ws + 8192;
  unsigned* cgenp  = (unsigned*)ws + 12288;
  ushort_t* h0f = (ushort_t*)(ws + kOffH0);     // [2][32][1024] fp16 (ping-pong)
  ushort_t* h1f = h0f + 2 * kB * kH;            // [2][32][1024] fp16
  float* gates0 = (float*)(h1f + 2 * kB * kH);
  float* gates1 = gates0 + kB * kNG;

  __shared__ __align__(16) char sb[kLdsBytes];
  uint4* wb4   = (uint4*)sb;
  float* redp  = (float*)(sb + kRedOff);
  float* ih_sh = (float*)(sb + kIhOff);
  float* fh_sh = (float*)(sb + kFhOff);

  const int lane = tid & 63;
  const int rt   = (tid >> 6) & 1;
  const int str  = tid >> 7;

  auto signal = [&](unsigned* arr, unsigned v) {
    asm volatile("s_waitcnt vmcnt(0)" ::: "memory");
    __syncthreads();
    if (tid == 0) st_flag(&arr[bid * 16], v);
  };
  // wave-scoped wait: each lane polls flag for (row = rt*16 + lane>>2,
  // q = lane&3) -> 64 flags/wave, no block barrier. Covers the wave's row-set
  // RAW (h data) and WAR (gates overwrite; B block (row,q) reads only row).
  auto wait_rows = [&](unsigned* arr, int baseBlk, int tgt) {
    const int idx = baseBlk + rt * 64 + lane;   // = base + row*4 + q
    while ((int)(ld_flag(&arr[idx * 16]) - (unsigned)tgt) < 0) {}
    asm volatile("" ::: "memory");
  };
  unsigned iseq = 0;
  auto initbar = [&]() {                        // r8-r15-proven two-hop shape
    ++iseq;
    asm volatile("s_waitcnt vmcnt(0)" ::: "memory");
    __syncthreads();
    if (bid == 0) {
      if (tid >= 1 && tid < kNBLK) {
        while (ld_flag(&cflags[tid * 16]) != iseq) __builtin_amdgcn_s_sleep(2);
      }
      __syncthreads();
      if (tid == 0) st_flag(cgenp, iseq);
    } else {
      if (tid == 0) {
        st_flag(&cflags[bid * 16], iseq);
        while (ld_flag(cgenp) != iseq) __builtin_amdgcn_s_sleep(2);
      }
      __syncthreads();
    }
    asm volatile("" ::: "memory");
  };

  // ---- A-phase block type ----
  int L, ntile, cb0;
  if (bid < 32)       { L = 0; ntile = 3; cb0 = bid * 48; }
  else if (bid < 120) { L = 0; ntile = 2; cb0 = 1536 + (bid - 32) * 32; }
  else                { L = 1; ntile = 2; cb0 = (bid - 120) * 32; }
  const int K   = L ? 2048 : 1536;
  const int ts4 = K * 2;
  const bool three = (ntile == 3);
  const int rstride = three ? 3 : 2;
  const ushort_t* wf = L ? wf1u : wf0u;
  const float* blp = L ? bl1 : bl0;
  const float* bvp = L ? bv1 : bv0;
  float* gatesL = L ? gates1 : gates0;

  const int r_   = rt * 16 + (lane & 15);
  const int koct = lane >> 4;
  const int colg0 = cb0 + (lane & 15);
  const int colg1 = cb0 + 16 + (lane & 15);
  const int colg2 = cb0 + 32 + (lane & 15);

  auto redsl = [&](int slot, int accIdx) -> float* {
    return &redp[(((slot * 2 + rt) * rstride) + accIdx) * 256 + lane * 4];
  };

  // ---- B-side hot/cold wait masks (precomputed; gate producers need e+1,
  //      everything else only covers the h WAR edge: e) ----
  const int pbB  = (bid & 127) >> 2;
  const int qq4B = bid & 3;
  bool hotB = false;        // for the flag this thread polls in its B-wait
  if (bid < 128) {
    // polls flagA[tid] for tid<256; producers are L0-A blocks 0..119
    if (tid < 120) {
      int cb = tid < 32 ? tid * 48 : 1536 + (tid - 32) * 32;
      int sp = tid < 32 ? 48 : 32;
#pragma unroll
      for (int q = 0; q < 4; ++q) {
        int a = q * 1024 + qq4B * 256;
        hotB = hotB || (cb < a + 256 && cb + sp > a);
      }
      hotB = hotB || (cb + sp > 4096);          // lvl-gate producers
    }
  } else {
    // polls flagA[(120+tid)*16] for tid<136; producers = L1-A blocks
    if (tid < 136) {
      int cb = tid * 32;
      int a = qq4B * 256;
#pragma unroll
      for (int q = 0; q < 4; ++q) {
        int aa = q * 1024 + a;
        hotB = hotB || (cb < aa + 256 && cb + 32 > aa);
      }
      hotB = hotB || (cb + 32 > 4096);
    }
  }

  // ---- one-time: build weight B-fragments in LDS (lane-linear) ----
  for (int tt = 0; tt < ntile; ++tt) {
    const int colb = cb0 + tt * 16;
    for (int idx = tid; idx < ts4; idx += kNTHR) {
      int m = idx >> 6, l2 = idx & 63;
      size_t off = (size_t)(colb + (l2 & 15)) * K + m * 32 + 8 * (l2 >> 4);
      wb4[tt * ts4 + idx] = *(const uint4*)(wf + off);
    }
  }
  const float b0w = (colg0 < 4096) ? blp[colg0] : bvp[colg0 - 4096];
  const float b1w = (colg1 < 4096) ? blp[colg1] : bvp[colg1 - 4096];
  const float b2w = three ? ((colg2 < 4096) ? blp[colg2] : bvp[colg2 - 4096]) : 0.f;
  __syncthreads();

  // ---- init: reset flags, zero h buffers, two central barriers ----
  if (tid == 0) { st_flag(&flagA[bid * 16], 0u); st_flag(&flagB[bid * 16], 0u); }
  { int idx = bid * kNTHR + tid;
    if (idx < 65536) st_wtu((unsigned*)h0f + idx, 0u); }
  float creg = 0.f;
  initbar();
  initbar();

  // phase-B cell update: single-wave softmax (r17-proven), 1 syncthreads
  auto cellB = [&](const float* gbase, ushort_t* hb, float& cr, float* outp, int t) {
    const float* gr = gbase + (size_t)pbB * kNG;
    const bool cl = tid < 256;
    float vi = 0.f, vf = 0.f, vo = 0.f, vg = 0.f;
    int j = qq4B * 256 + tid;
    if (cl) {
      vi = ld_coh(gr + j);
      vf = ld_coh(gr + kH + j);
      vo = ld_coh(gr + 2 * kH + j);
      vg = ld_coh(gr + 3 * kH + j);
    }
    if (tid < 64) {
      float a0i = ld_coh(gr + 4096 + 2 * tid);
      float a1i = ld_coh(gr + 4096 + 2 * tid + 1);
      float a0f = ld_coh(gr + 4096 + kLV + 2 * tid);
      float a1f = ld_coh(gr + 4096 + kLV + 2 * tid + 1);
      float mi = fmaxf(a0i, a1i), mf = fmaxf(a0f, a1f);
#pragma unroll
      for (int d = 32; d > 0; d >>= 1) {
        mi = fmaxf(mi, __shfl_xor(mi, d));
        mf = fmaxf(mf, __shfl_xor(mf, d));
      }
      float e0i = __expf(a0i - mi), e1i = __expf(a1i - mi);
      float e0f = __expf(a0f - mf), e1f = __expf(a1f - mf);
      float si2 = e0i + e1i, sf2 = e0f + e1f;
      float Pi = si2, Pf = sf2;
#pragma unroll
      for (int d = 1; d < 64; d <<= 1) {
        float ni = __shfl_up(Pi, d);
        float nf = __shfl_up(Pf, d);
        if (tid >= d) { Pi += ni; Pf += nf; }
      }
      float Si = __shfl(Pi, 63), Sf = __shfl(Pf, 63);
      float pri = Pi - si2, prf = Pf - sf2;
      ih_sh[2 * tid]     = (prf + e0f) / Sf;
      ih_sh[2 * tid + 1] = (prf + e0f + e1f) / Sf;
      fh_sh[2 * tid]     = (Si - pri) / Si;
      fh_sh[2 * tid + 1] = (Si - pri - e0i) / Si;
    }
    __syncthreads();
    if (cl) {
      float i_ = 1.f / (1.f + __expf(-vi));
      float f_ = 1.f / (1.f + __expf(-vf));
      float o_ = 1.f / (1.f + __expf(-vo));
      float g_ = tanhf(vg);
      int l2 = j >> 3;
      float ih = ih_sh[l2], fh = fh_sh[l2];
      float w  = ih * fh;
      float cold = cr;
      float cn = w * (f_ * cold + i_ * g_) + (fh - w) * cold + (ih - w) * g_;
      float hn = o_ * tanhf(cn);
      cr = cn;
      float hnn = __shfl_xor(hn, 1);
      if (!(tid & 1))
        st_wtu((unsigned*)hb + ((size_t)pbB * kH + j) / 2, pkrtz(hn, hnn));
      if (outp) outp[((size_t)pbB * kT + t) * kH + j] = hn;  // plain write-back
    }
  };

  for (int e = 0; e <= kT; ++e) {
    const bool actA = L ? (e >= 1) : (e < kT);
    const size_t wpar = (size_t)(e & 1) * kB * kH;
    const size_t rpar = (size_t)((e + 1) & 1) * kB * kH;

    // ========== Phase A ==========
    if (actA) {
      floatx4 a0 = {0.f,0.f,0.f,0.f}, a1 = a0, a2 = a0;
      if (L == 0) {
        // x segment BEFORE the wait (input-only; overlaps B stragglers)
        const float* bx = x + ((size_t)r_ * kT + e) * kD + str * 32 + koct * 8;
        vfloat4 vx[8];
#pragma unroll
        for (int j = 0; j < 4; ++j) {
          vx[2*j]   = *(const vfloat4*)(bx + j * 128);
          vx[2*j+1] = *(const vfloat4*)(bx + j * 128 + 4);
        }
        uint4 pa[4];
#pragma unroll
        for (int j = 0; j < 4; ++j) pa[j] = pack2(vx[2*j], vx[2*j+1]);
#pragma unroll
        for (int j = 0; j < 4; ++j) {
          const int m = str + 4 * j;
          a0 = mfma16(pa[j], wb4[m * 64 + lane], a0);
          a1 = mfma16(pa[j], wb4[ts4 + m * 64 + lane], a1);
          if (three) a2 = mfma16(pa[j], wb4[2 * ts4 + m * 64 + lane], a2);
        }
        // h0 edge: wave-scoped (own rows' L0-B producers + gates0 WAR)
        if (e > 0) wait_rows(flagB, 0, e + 1);
        uint4 ph[8];
        ld8h(ph, h0f + rpar + (size_t)r_ * kH + str * 32 + koct * 8);
#pragma unroll
        for (int j = 0; j < 8; ++j) {
          const int m = 16 + str + 4 * j;
          a0 = mfma16(ph[j], wb4[m * 64 + lane], a0);
          a1 = mfma16(ph[j], wb4[ts4 + m * 64 + lane], a1);
          if (three) a2 = mfma16(ph[j], wb4[2 * ts4 + m * 64 + lane], a2);
        }
      } else {
        // h0 edge (slack) then h1 edge (tight), both wave-scoped
        wait_rows(flagB, 0, e + 1);
        uint4 pa[8];
        ld8h(pa, h0f + rpar + (size_t)r_ * kH + str * 32 + koct * 8);
#pragma unroll
        for (int j = 0; j < 8; ++j) {
          const int m = str + 4 * j;
          a0 = mfma16(pa[j], wb4[m * 64 + lane], a0);
          a1 = mfma16(pa[j], wb4[ts4 + m * 64 + lane], a1);
        }
        wait_rows(flagB, 128, e + 1);
        uint4 pb[8];
        ld8h(pb, h1f + rpar + (size_t)r_ * kH + str * 32 + koct * 8);
#pragma unroll
        for (int j = 0; j < 8; ++j) {
          const int m = 32 + str + 4 * j;
          a0 = mfma16(pb[j], wb4[m * 64 + lane], a0);
          a1 = mfma16(pb[j], wb4[ts4 + m * 64 + lane], a1);
        }
      }
      // K-stripe reduce (r16-r18-proven)
      if (!three) {
        if (str != 0) {
          *(floatx4*)redsl(str - 1, 0) = a0;
          *(floatx4*)redsl(str - 1, 1) = a1;
        }
        __syncthreads();
        if (str == 0) {
#pragma unroll
          for (int s2 = 0; s2 < 3; ++s2) {
            a0 += *(const floatx4*)redsl(s2, 0);
            a1 += *(const floatx4*)redsl(s2, 1);
          }
        }
      } else {
        if (str == 1 || str == 2) {
          *(floatx4*)redsl(str - 1, 0) = a0;
          *(floatx4*)redsl(str - 1, 1) = a1;
          *(floatx4*)redsl(str - 1, 2) = a2;
        }
        __syncthreads();
        if (str == 0) {
#pragma unroll
          for (int s2 = 0; s2 < 2; ++s2) {
            a0 += *(const floatx4*)redsl(s2, 0);
            a1 += *(const floatx4*)redsl(s2, 1);
            a2 += *(const floatx4*)redsl(s2, 2);
          }
        }
        __syncthreads();
        if (str == 3) {
          *(floatx4*)redsl(0, 0) = a0;
          *(floatx4*)redsl(0, 1) = a1;
          *(floatx4*)redsl(0, 2) = a2;
        }
        __syncthreads();
        if (str == 0) {
          a0 += *(const floatx4*)redsl(0, 0);
          a1 += *(const floatx4*)redsl(0, 1);
          a2 += *(const floatx4*)redsl(0, 2);
        }
      }
      if (str == 0) {
        const int rb = rt * 16 + koct * 4;
#pragma unroll
        for (int r = 0; r < 4; ++r)
          st_wt(gatesL + (size_t)(rb + r) * kNG + colg0, a0[r] + b0w);
#pragma unroll
        for (int r = 0; r < 4; ++r)
          st_wt(gatesL + (size_t)(rb + r) * kNG + colg1, a1[r] + b1w);
        if (three) {
#pragma unroll
          for (int r = 0; r < 4; ++r)
            st_wt(gatesL + (size_t)(rb + r) * kNG + colg2, a2[r] + b2w);
        }
      }
    }
    signal(flagA, (unsigned)(e + 1));

    // ========== Phase B (hot/cold targeted waits) ==========
    if (bid < 128) {
      if (e < kT) {
        if (tid < 256) {
          int tgt = hotB ? e + 1 : e;
          while ((int)(ld_flag(&flagA[tid * 16]) - (unsigned)tgt) < 0) {}
        }
        __syncthreads();
        asm volatile("" ::: "memory");
        cellB(gates0, h0f + wpar, creg, nullptr, e);
      }
    } else {
      if (e >= 1) {
        if (tid < 136) {
          int tgt = hotB ? e + 1 : e;
          while ((int)(ld_flag(&flagA[(120 + tid) * 16]) - (unsigned)tgt) < 0) {}
        }
        __syncthreads();
        asm volatile("" ::: "memory");
        cellB(gates1, h1f + wpar, creg, out, e - 1);
      }
    }
    signal(flagB, (unsigned)(e + 2));
  }
}

extern "C" void kernel_launch(void* const* d_in, const int* in_sizes, int n_in,
                              void* d_out, int out_size, void* d_ws, size_t ws_size,
                              hipStream_t stream) {
  const float* x   = (const float*)d_in[0];
  const float* Wl0 = (const float*)d_in[1];
  const float* bl0 = (const float*)d_in[2];
  const float* Wv0 = (const float*)d_in[3];
  const float* bv0 = (const float*)d_in[4];
  const float* Wl1 = (const float*)d_in[5];
  const float* bl1 = (const float*)d_in[6];
  const float* Wv1 = (const float*)d_in[7];
  const float* bv1 = (const float*)d_in[8];
  (void)in_sizes; (void)n_in; (void)out_size; (void)ws_size;

  float* ws = (float*)d_ws;
  const size_t kOffWFf = (size_t)kOffH0 + 32768 + 32768 + 2 * (size_t)kB * kNG;
  ushort_t* wf0 = (ushort_t*)(ws + kOffWFf);               // [4352][1536] fp16
  ushort_t* wf1 = wf0 + (size_t)4352 * 1536;               // [4352][2048] fp16

  {
    int n;
    n = 4096 * 1536 / 8;
    cvt_fp16_kernel<<<(n + 255) / 256, 256, 0, stream>>>(Wl0, wf0, n);
    n = 256 * 1536 / 8;
    cvt_fp16_kernel<<<(n + 255) / 256, 256, 0, stream>>>(
        Wv0, wf0 + (size_t)4096 * 1536, n);
    n = 4096 * 2048 / 8;
    cvt_fp16_kernel<<<(n + 255) / 256, 256, 0, stream>>>(Wl1, wf1, n);
    n = 256 * 2048 / 8;
    cvt_fp16_kernel<<<(n + 255) / 256, 256, 0, stream>>>(
        Wv1, wf1 + (size_t)4096 * 2048, n);
  }

  onlstm_kernel<<<dim3(kNBLK), dim3(kNTHR), 0, stream>>>(
      x, bl0, bv0, bl1, bv1, wf0, wf1, (float*)d_out, ws);
}